// Round 3
// baseline (2253.573 us; speedup 1.0000x reference)
//
#include <hip/hip_runtime.h>
#include <cstdint>

// VisionMambaLite forward on gfx950.
// Inputs/output are FLOAT32 (per reference). GEMMs run bf16 MFMA 16x16x32
// with fp32 accum: weights converted f32->bf16 per layer into workspace,
// activations kept bf16 between ops. M=12544=98*128 exactly; all K,N
// multiples of 64/128 -> no bounds checks.

using u16 = unsigned short;
typedef __attribute__((ext_vector_type(8))) short   bfrag;   // 8 bf16 = 4 VGPR
typedef __attribute__((ext_vector_type(4))) float   ffrag;   // 4 f32 acc
typedef __attribute__((ext_vector_type(8))) u16     u16x8;

__device__ __forceinline__ float b2f(u16 u) {
  union { float f; uint32_t i; } c; c.i = ((uint32_t)u) << 16; return c.f;
}
__device__ __forceinline__ u16 f2b(float f) {
  union { float f; uint32_t i; } c; c.f = f;
  uint32_t r = c.i + 0x7FFFu + ((c.i >> 16) & 1u);
  return (u16)(r >> 16);
}

// async global->LDS, 16B/lane, dest = wave-uniform base + lane*16
__device__ __forceinline__ void gl_lds16(const u16* g, u16* l) {
  __builtin_amdgcn_global_load_lds(
      (const __attribute__((address_space(1))) void*)g,
      (__attribute__((address_space(3))) void*)l,
      16, 0, 0);
}

// ---------------------------------------------------------------------------
// GEMM: C[m,n] = sum_k A[m,k] * W[n,k]  (A: 12544 x K, W: N x K, bf16)
// Tile 128x128, BK=64. 4 waves, each 64x64 (4x4 MFMA 16x16x32 frags).
// LDS: [row][chunk ^ (row&7)] (8-half chunks) -> global_load_lds compatible,
// 2-way-max bank conflicts on ds_read_b128.
// EPI: 1 = bf16 store C[m*ldc+col+coloff]
//      2 = bf16 store with h<->w involution on row (vertical scatter)
// AMAP: 0 identity A rows; 1 = h<->w involution gather on A rows.
// ---------------------------------------------------------------------------
template<int EPI, int AMAP>
__global__ __launch_bounds__(256, 2)
void gemm_bt(const u16* __restrict__ A, const u16* __restrict__ W,
             u16* __restrict__ Cb, int K, int ldc, int coloff)
{
  __shared__ u16 As[128 * 64];
  __shared__ u16 Bs[128 * 64];

  const int tid  = threadIdx.x;
  const int lane = tid & 63;
  const int wv   = tid >> 6;      // 0..3
  const int wm   = wv >> 1;       // 0..1
  const int wn   = wv & 1;        // 0..1
  const int m0   = blockIdx.y * 128;
  const int n0   = blockIdx.x * 128;

  // staging geometry: per wave-instr, 64 lanes cover 8 rows x 8 chunks
  const int lr   = lane >> 3;            // row-in-group 0..7
  const int lc   = lane & 7;             // dest chunk 0..7
  const int kcol = (lc ^ lr) << 3;       // swizzled source k-chunk * 8

  int arow[4], brow[4];
#pragma unroll
  for (int i = 0; i < 4; ++i) {
    int r = m0 + wv * 32 + i * 8 + lr;
    if (AMAP == 1) {
      int b = r / 196; int q = r - b * 196;
      int wq = q / 14; int hq = q - wq * 14;
      r = b * 196 + hq * 14 + wq;
    }
    arow[i] = r;
    brow[i] = n0 + wv * 32 + i * 8 + lr;
  }

  const ffrag fz = {0.f, 0.f, 0.f, 0.f};
  ffrag acc[4][4];
#pragma unroll
  for (int i = 0; i < 4; ++i)
#pragma unroll
    for (int j = 0; j < 4; ++j) acc[i][j] = fz;

  const int fr = lane & 15;   // frag row/col within 16
  const int fq = lane >> 4;   // quad 0..3

  for (int kb = 0; kb < K; kb += 64) {
#pragma unroll
    for (int i = 0; i < 4; ++i)
      gl_lds16(A + (size_t)arow[i] * K + kb + kcol, &As[(wv * 4 + i) * 512]);
#pragma unroll
    for (int i = 0; i < 4; ++i)
      gl_lds16(W + (size_t)brow[i] * K + kb + kcol, &Bs[(wv * 4 + i) * 512]);
    __syncthreads();

#pragma unroll
    for (int ks = 0; ks < 2; ++ks) {
      bfrag af[4], bfr[4];
#pragma unroll
      for (int t = 0; t < 4; ++t) {
        int r  = wm * 64 + t * 16 + fr;
        int ca = ((ks * 4 + fq) ^ (r & 7)) << 3;
        af[t]  = *(const bfrag*)&As[r * 64 + ca];
        int n  = wn * 64 + t * 16 + fr;
        int cb = ((ks * 4 + fq) ^ (n & 7)) << 3;
        bfr[t] = *(const bfrag*)&Bs[n * 64 + cb];
      }
#pragma unroll
      for (int i = 0; i < 4; ++i)
#pragma unroll
        for (int j = 0; j < 4; ++j)
          acc[i][j] = __builtin_amdgcn_mfma_f32_16x16x32_bf16(
              af[i], bfr[j], acc[i][j], 0, 0, 0);
    }
    __syncthreads();
  }

  // epilogue: C/D layout col=lane&15, row=quad*4+reg (m89-verified)
#pragma unroll
  for (int i = 0; i < 4; ++i) {
#pragma unroll
    for (int j = 0; j < 4; ++j) {
#pragma unroll
      for (int rg = 0; rg < 4; ++rg) {
        int row = m0 + wm * 64 + i * 16 + fq * 4 + rg;
        int col = n0 + wn * 64 + j * 16 + fr + coloff;
        int orow = row;
        if (EPI == 2) {
          int b = row / 196; int q = row - b * 196;
          int wq = q / 14; int hq = q - wq * 14;
          orow = b * 196 + hq * 14 + wq;
        }
        Cb[(size_t)orow * ldc + col] = f2b(acc[i][j][rg]);
      }
    }
  }
}

// ---------------------------------------------------------------------------
// weight conversion f32 -> bf16, 7 regions per layer (contiguous dest WB)
// region order: mh_in 786432 | mh_dt 589824 | mh_out 393216 |
//               mv_in 786432 | mv_dt 589824 | mv_out 393216 | fus 524288
// total 4,063,232 elems; 8 per thread
// ---------------------------------------------------------------------------
__global__ __launch_bounds__(256)
void k_cvt7(const float* __restrict__ s0, const float* __restrict__ s1,
            const float* __restrict__ s2, const float* __restrict__ s3,
            const float* __restrict__ s4, const float* __restrict__ s5,
            const float* __restrict__ s6, u16* __restrict__ dst)
{
  int e = (blockIdx.x * 256 + threadIdx.x) * 8;   // < 4063232
  const float* s; int off;
  if      (e <  786432) { s = s0; off = e; }
  else if (e < 1376256) { s = s1; off = e -  786432; }
  else if (e < 1769472) { s = s2; off = e - 1376256; }
  else if (e < 2555904) { s = s3; off = e - 1769472; }
  else if (e < 3145728) { s = s4; off = e - 2555904; }
  else if (e < 3538944) { s = s5; off = e - 3145728; }
  else                  { s = s6; off = e - 3538944; }
  float4 a = *(const float4*)(s + off);
  float4 b = *(const float4*)(s + off + 4);
  u16x8 o;
  o[0] = f2b(a.x); o[1] = f2b(a.y); o[2] = f2b(a.z); o[3] = f2b(a.w);
  o[4] = f2b(b.x); o[5] = f2b(b.y); o[6] = f2b(b.z); o[7] = f2b(b.w);
  *(u16x8*)(dst + e) = o;
}

// single-region f32 -> bf16 (patch_w)
__global__ __launch_bounds__(256)
void k_cvt1(const float* __restrict__ s, u16* __restrict__ dst)
{
  int e = (blockIdx.x * 256 + threadIdx.x) * 8;
  float4 a = *(const float4*)(s + e);
  float4 b = *(const float4*)(s + e + 4);
  u16x8 o;
  o[0] = f2b(a.x); o[1] = f2b(a.y); o[2] = f2b(a.z); o[3] = f2b(a.w);
  o[4] = f2b(b.x); o[5] = f2b(b.y); o[6] = f2b(b.z); o[7] = f2b(b.w);
  *(u16x8*)(dst + e) = o;
}

// ---------------------------------------------------------------------------
// im2col: im[p, k=c*256+i*16+j] = x[b, c, ph*16+i, pw*16+j], 8 elems/thread
// x is f32; im is bf16
// ---------------------------------------------------------------------------
__global__ __launch_bounds__(256) void k_im2col(const float* __restrict__ x,
                                                u16* __restrict__ im)
{
  int idx = blockIdx.x * 256 + threadIdx.x;     // 12544*96
  int r = idx % 96, p = idx / 96;
  int b = p / 196, q = p - b * 196;
  int ph = q / 14, pw = q - ph * 14;
  int k = r * 8;
  int c = k >> 8, k2 = k & 255;
  int i = k2 >> 4, j = k2 & 15;                 // j in {0,8}
  const float* src = x + (((size_t)(b * 3 + c) * 224 + ph * 16 + i) * 224
                          + pw * 16 + j);
  float4 a = *(const float4*)src;
  float4 d = *(const float4*)(src + 4);
  u16x8 o;
  o[0] = f2b(a.x); o[1] = f2b(a.y); o[2] = f2b(a.z); o[3] = f2b(a.w);
  o[4] = f2b(d.x); o[5] = f2b(d.y); o[6] = f2b(d.z); o[7] = f2b(d.w);
  *(u16x8*)(im + (size_t)p * 768 + k) = o;
}

// TOK[p,n] += patch_b[n] + pos_embed[1 + p%196, n]   (bf16 RMW, 8/thread)
__global__ __launch_bounds__(256) void k_addbias(u16* __restrict__ TOK,
                                                 const float* __restrict__ pb,
                                                 const float* __restrict__ pos)
{
  int idx = blockIdx.x * 256 + threadIdx.x;     // 12544*64
  int p = idx >> 6, n = (idx & 63) * 8;
  int tpos = 1 + (p % 196);
  u16x8 t = *(u16x8*)(TOK + (size_t)p * 512 + n);
  const float* pbv = pb + n;
  const float* pv  = pos + (size_t)tpos * 512 + n;
  u16x8 o;
#pragma unroll
  for (int i = 0; i < 8; ++i) o[i] = f2b(b2f(t[i]) + pbv[i] + pv[i]);
  *(u16x8*)(TOK + (size_t)p * 512 + n) = o;
}

// in-place LN over 512 cols, one wave per row, 8 elems/lane (bf16; f32 params)
__global__ __launch_bounds__(256) void k_ln(u16* __restrict__ T,
                                            const float* __restrict__ w,
                                            const float* __restrict__ b)
{
  int row  = blockIdx.x * 4 + (threadIdx.x >> 6);
  int lane = threadIdx.x & 63;
  int base = lane * 8;
  u16* p = T + (size_t)row * 512 + base;
  u16x8 t = *(u16x8*)p;
  float v[8]; float s = 0.f, qq = 0.f;
#pragma unroll
  for (int i = 0; i < 8; ++i) { v[i] = b2f(t[i]); s += v[i]; qq += v[i] * v[i]; }
#pragma unroll
  for (int o = 32; o; o >>= 1) { s += __shfl_xor(s, o, 64); qq += __shfl_xor(qq, o, 64); }
  float mean = s * (1.f / 512.f);
  float rstd = rsqrtf(qq * (1.f / 512.f) - mean * mean + 1e-5f);
  u16x8 ov;
#pragma unroll
  for (int i = 0; i < 8; ++i)
    ov[i] = f2b((v[i] - mean) * rstd * w[base + i] + b[base + i]);
  *(u16x8*)p = ov;
}

// TOK = LN(YF + fus_b + TOK) with ss params (in place)
__global__ __launch_bounds__(256) void k_ln_fuse(const u16* __restrict__ YF,
                                                 u16* __restrict__ TOK,
                                                 const float* __restrict__ fb,
                                                 const float* __restrict__ w,
                                                 const float* __restrict__ b)
{
  int row  = blockIdx.x * 4 + (threadIdx.x >> 6);
  int lane = threadIdx.x & 63;
  int base = lane * 8;
  const u16* yf = YF + (size_t)row * 512 + base;
  u16* tp = TOK + (size_t)row * 512 + base;
  u16x8 yv = *(const u16x8*)yf;
  u16x8 tv = *(u16x8*)tp;
  float v[8]; float s = 0.f, qq = 0.f;
#pragma unroll
  for (int i = 0; i < 8; ++i) {
    v[i] = b2f(yv[i]) + fb[base + i] + b2f(tv[i]);
    s += v[i]; qq += v[i] * v[i];
  }
#pragma unroll
  for (int o = 32; o; o >>= 1) { s += __shfl_xor(s, o, 64); qq += __shfl_xor(qq, o, 64); }
  float mean = s * (1.f / 512.f);
  float rstd = rsqrtf(qq * (1.f / 512.f) - mean * mean + 1e-5f);
  u16x8 ov;
#pragma unroll
  for (int i = 0; i < 8; ++i)
    ov[i] = f2b((v[i] - mean) * rstd * w[base + i] + b[base + i]);
  *(u16x8*)tp = ov;
}

// conv3 + silu along L=14 (bf16 act, f32 params). XZ xi-half is input.
__global__ __launch_bounds__(256) void k_conv(const u16* __restrict__ XZ,
                                              const float* __restrict__ cw,
                                              const float* __restrict__ cb,
                                              u16* __restrict__ XC)
{
  int idx = blockIdx.x * 256 + threadIdx.x;   // 896*768
  int d = idx % 768, sq = idx / 768;
  const u16* xi = XZ + (size_t)sq * 14 * 1536 + d;
  float w0 = cw[d * 3 + 0], w1 = cw[d * 3 + 1], w2 = cw[d * 3 + 2];
  float bb = cb[d];
  float prev = 0.f, cur = b2f(xi[0]), nxt;
#pragma unroll
  for (int l = 0; l < 14; ++l) {
    nxt = (l < 13) ? b2f(xi[(size_t)(l + 1) * 1536]) : 0.f;
    float u = prev * w0 + cur * w1 + nxt * w2 + bb;
    float sv = u / (1.f + expf(-u));
    XC[((size_t)sq * 14 + l) * 768 + d] = f2b(sv);
    prev = cur; cur = nxt;
  }
}

// selective-scan: dt=softplus(dtraw+db); Ae=exp(A dt); run=cumsum(xc dt Ae);
// y = (run*Ae + xc*D) * silu(z). In-place: XC holds xc in, y out.
__global__ __launch_bounds__(256) void k_scan(const u16* __restrict__ XZ,
                                              u16* __restrict__ XC,
                                              const float* __restrict__ dtb,
                                              const float* __restrict__ Ap,
                                              const float* __restrict__ Dp)
{
  int idx = blockIdx.x * 256 + threadIdx.x;   // 896*768
  int d = idx % 768, sq = idx / 768;
  float db = dtb[d], Av = Ap[d], Dv = Dp[d];
  float run = 0.f;
#pragma unroll
  for (int l = 0; l < 14; ++l) {
    size_t m = (size_t)sq * 14 + l;
    float xc = b2f(XC[m * 768 + d]);
    float dtr = b2f(XZ[m * 1536 + d]) + db;
    float dt = (dtr > 20.f) ? dtr : log1pf(expf(dtr));
    float ae = expf(Av * dt);
    run += xc * dt * ae;
    float z = b2f(XZ[m * 1536 + 768 + d]);
    float y = (run * ae + xc * Dv) * (z / (1.f + expf(-z)));
    XC[m * 768 + d] = f2b(y);
  }
}

// cls token path: batch-invariant, evolve one 512-vec through 6 layers (f32).
__global__ void k_cls(const float* __restrict__ cls_tok,
                      const float* __restrict__ pos,
                      const float* __restrict__ bw, const float* __restrict__ bb,
                      float* __restrict__ CLS)
{
  __shared__ float rs[8], rq[8], stat[2];
  int n = threadIdx.x;                        // 512 threads
  float v = cls_tok[n] + pos[n];
  for (int l = 0; l < 6; ++l) {
    float s = v, q = v * v;
#pragma unroll
    for (int o = 32; o; o >>= 1) { s += __shfl_xor(s, o, 64); q += __shfl_xor(q, o, 64); }
    if ((n & 63) == 0) { rs[n >> 6] = s; rq[n >> 6] = q; }
    __syncthreads();
    if (n == 0) {
      float S = 0.f, Q = 0.f;
      for (int i = 0; i < 8; ++i) { S += rs[i]; Q += rq[i]; }
      float m = S * (1.f / 512.f);
      stat[0] = m; stat[1] = rsqrtf(Q * (1.f / 512.f) - m * m + 1e-5f);
    }
    __syncthreads();
    float u = (v - stat[0]) * stat[1] * bw[l * 512 + n] + bb[l * 512 + n];
    v = v + u;
    __syncthreads();
  }
  CLS[n] = v;
}

// final LN over 64*197 tokens -> f32 out; t==0 uses the shared CLS vec.
__global__ __launch_bounds__(256) void k_final(const u16* __restrict__ TOK,
                                               const float* __restrict__ CLS,
                                               const float* __restrict__ w,
                                               const float* __restrict__ b,
                                               float* __restrict__ out)
{
  int row  = blockIdx.x * 4 + (threadIdx.x >> 6);   // < 12608
  int lane = threadIdx.x & 63;
  int bi = row / 197;
  int t  = row - bi * 197;
  int base = lane * 8;
  float v[8]; float s = 0.f, qq = 0.f;
  if (t == 0) {
#pragma unroll
    for (int i = 0; i < 8; ++i) v[i] = CLS[base + i];
  } else {
    const u16* src = TOK + ((size_t)bi * 196 + (t - 1)) * 512 + base;
    u16x8 tv = *(const u16x8*)src;
#pragma unroll
    for (int i = 0; i < 8; ++i) v[i] = b2f(tv[i]);
  }
#pragma unroll
  for (int i = 0; i < 8; ++i) { s += v[i]; qq += v[i] * v[i]; }
#pragma unroll
  for (int o = 32; o; o >>= 1) { s += __shfl_xor(s, o, 64); qq += __shfl_xor(qq, o, 64); }
  float mean = s * (1.f / 512.f);
  float rstd = rsqrtf(qq * (1.f / 512.f) - mean * mean + 1e-5f);
  float* op = out + (size_t)row * 512 + base;
#pragma unroll
  for (int i = 0; i < 8; ++i)
    op[i] = (v[i] - mean) * rstd * w[base + i] + b[base + i];
}

// ---------------------------------------------------------------------------
extern "C" void kernel_launch(void* const* d_in, const int* in_sizes, int n_in,
                              void* d_out, int out_size, void* d_ws, size_t ws_size,
                              hipStream_t stream)
{
  const float* x        = (const float*)d_in[0];
  const float* patch_w  = (const float*)d_in[1];
  const float* patch_b  = (const float*)d_in[2];
  const float* cls_tok  = (const float*)d_in[3];
  const float* pos      = (const float*)d_in[4];
  const float* blk_w    = (const float*)d_in[5];
  const float* blk_b    = (const float*)d_in[6];
  const float* mh_in_w  = (const float*)d_in[7];
  const float* mh_out_w = (const float*)d_in[8];
  const float* mh_cw    = (const float*)d_in[9];
  const float* mh_cb    = (const float*)d_in[10];
  const float* mh_dtw   = (const float*)d_in[11];
  const float* mh_dtb   = (const float*)d_in[12];
  const float* mh_A     = (const float*)d_in[13];
  const float* mh_D     = (const float*)d_in[14];
  const float* mv_in_w  = (const float*)d_in[15];
  const float* mv_out_w = (const float*)d_in[16];
  const float* mv_cw    = (const float*)d_in[17];
  const float* mv_cb    = (const float*)d_in[18];
  const float* mv_dtw   = (const float*)d_in[19];
  const float* mv_dtb   = (const float*)d_in[20];
  const float* mv_A     = (const float*)d_in[21];
  const float* mv_D     = (const float*)d_in[22];
  const float* fus_w    = (const float*)d_in[23];
  const float* fus_b    = (const float*)d_in[24];
  const float* ss_w     = (const float*)d_in[25];
  const float* ss_b     = (const float*)d_in[26];
  const float* fn_w     = (const float*)d_in[27];
  const float* fn_b     = (const float*)d_in[28];

  // workspace layout (bytes), total ~104.5 MB, all 256-aligned:
  char* ws = (char*)d_ws;
  u16*   TOK = (u16*)  (ws);                  // 12544x512  bf16  12,845,056
  u16*   XZ  = (u16*)  (ws + 12845056);       // 12544x1536 bf16  38,535,168
  u16*   XC  = (u16*)  (ws + 51380224);       // 12544x768  bf16  19,267,584
  u16*   YC  = (u16*)  (ws + 70647808);       // 12544x1024 bf16  25,690,112
  u16*   WB  = (u16*)  (ws + 96337920);       // per-layer bf16 weights 8,126,464
  float* CLS = (float*)(ws + 104464384);      // 512 f32
  u16*   IM  = XC;                            // im2col aliases XC (pre-layer)
  u16*   YF  = XZ;                            // fusion out aliases XZ

  // per-layer WB offsets (elements)
  const size_t oMHI = 0,       oMHD = 786432,  oMHO = 1376256;
  const size_t oMVI = 1769472, oMVD = 2555904, oMVO = 3145728;
  const size_t oFUS = 3538944;

  // patch embed: convert patch_w into WB, im2col, GEMM, bias/pos
  k_cvt1<<<192, 256, 0, stream>>>(patch_w, WB);
  k_im2col<<<4704, 256, 0, stream>>>(x, IM);
  gemm_bt<1, 0><<<dim3(4, 98), 256, 0, stream>>>(IM, WB, TOK, 768, 512, 0);
  k_addbias<<<3136, 256, 0, stream>>>(TOK, patch_b, pos);
  k_cls<<<1, 512, 0, stream>>>(cls_tok, pos, blk_w, blk_b, CLS);

  for (int L = 0; L < 6; ++L) {
    k_cvt7<<<1984, 256, 0, stream>>>(
        mh_in_w + (size_t)L * 786432, mh_dtw + (size_t)L * 589824,
        mh_out_w + (size_t)L * 393216,
        mv_in_w + (size_t)L * 786432, mv_dtw + (size_t)L * 589824,
        mv_out_w + (size_t)L * 393216,
        fus_w + (size_t)L * 524288, WB);

    // TOK <- LN(TOK)  (p2 = pn is the residual, so in-place is exact)
    k_ln<<<3136, 256, 0, stream>>>(TOK, blk_w + L * 512, blk_b + L * 512);

    // horizontal mamba
    gemm_bt<1, 0><<<dim3(12, 98), 256, 0, stream>>>(TOK, WB + oMHI, XZ, 512, 1536, 0);
    k_conv<<<2688, 256, 0, stream>>>(XZ, mh_cw + L * 2304, mh_cb + L * 768, XC);
    gemm_bt<1, 0><<<dim3(6, 98), 256, 0, stream>>>(XC, WB + oMHD, XZ, 768, 1536, 0);
    k_scan<<<2688, 256, 0, stream>>>(XZ, XC, mh_dtb + L * 768, mh_A + L * 768,
                                     mh_D + L * 768);
    gemm_bt<1, 0><<<dim3(4, 98), 256, 0, stream>>>(XC, WB + oMHO, YC, 768, 1024, 0);

    // vertical mamba (gather h<->w on in-proj A rows, scatter on out-proj)
    gemm_bt<1, 1><<<dim3(12, 98), 256, 0, stream>>>(TOK, WB + oMVI, XZ, 512, 1536, 0);
    k_conv<<<2688, 256, 0, stream>>>(XZ, mv_cw + L * 2304, mv_cb + L * 768, XC);
    gemm_bt<1, 0><<<dim3(6, 98), 256, 0, stream>>>(XC, WB + oMVD, XZ, 768, 1536, 0);
    k_scan<<<2688, 256, 0, stream>>>(XZ, XC, mv_dtb + L * 768, mv_A + L * 768,
                                     mv_D + L * 768);
    gemm_bt<2, 0><<<dim3(4, 98), 256, 0, stream>>>(XC, WB + oMVO, YC, 768, 1024, 512);

    // fusion + residual LN (YF aliases XZ, dead after v-scan)
    gemm_bt<1, 0><<<dim3(4, 98), 256, 0, stream>>>(YC, WB + oFUS, YF, 1024, 512, 0);
    k_ln_fuse<<<3136, 256, 0, stream>>>(YF, TOK, fus_b + L * 512, ss_w + L * 512,
                                        ss_b + L * 512);
  }

  k_final<<<3152, 256, 0, stream>>>(TOK, CLS, fn_w, fn_b, (float*)d_out);
  (void)in_sizes; (void)n_in; (void)out_size; (void)ws_size;
}

// Round 4
// 1709.106 us; speedup vs baseline: 1.3186x; 1.3186x over previous
//
#include <hip/hip_runtime.h>
#include <cstdint>

// VisionMambaLite forward on gfx950.
// Inputs/output are FLOAT32 (per reference). GEMMs run bf16 MFMA 16x16x32
// with fp32 accum: weights converted f32->bf16 per layer into workspace,
// activations kept bf16 between ops. M=12544=98*128 exactly; all K,N
// multiples of 64/128 -> no bounds checks.
// R4: scan/conv use HW transcendentals (v_exp_f32/v_log_f32/v_rcp_f32)
// instead of libm expf/log1pf + fdiv — scan was 350 VALU-lane-ops/step.

using u16 = unsigned short;
typedef __attribute__((ext_vector_type(8))) short   bfrag;   // 8 bf16 = 4 VGPR
typedef __attribute__((ext_vector_type(4))) float   ffrag;   // 4 f32 acc
typedef __attribute__((ext_vector_type(8))) u16     u16x8;

__device__ __forceinline__ float b2f(u16 u) {
  union { float f; uint32_t i; } c; c.i = ((uint32_t)u) << 16; return c.f;
}
__device__ __forceinline__ u16 f2b(float f) {
  union { float f; uint32_t i; } c; c.f = f;
  uint32_t r = c.i + 0x7FFFu + ((c.i >> 16) & 1u);
  return (u16)(r >> 16);
}

// fast HW transcendentals
#define LOG2E 1.44269504f
#define LN2   0.69314718f
__device__ __forceinline__ float fexp(float x) {
  return __builtin_amdgcn_exp2f(x * LOG2E);
}
__device__ __forceinline__ float fsigmoid(float x) {
  return __builtin_amdgcn_rcpf(1.f + __builtin_amdgcn_exp2f(-x * LOG2E));
}
__device__ __forceinline__ float fsilu(float x) { return x * fsigmoid(x); }
__device__ __forceinline__ float fsoftplus(float x) {
  float e = __builtin_amdgcn_exp2f(-fabsf(x) * LOG2E);
  return fmaxf(x, 0.f) + LN2 * __builtin_amdgcn_logf(1.f + e);
}

// async global->LDS, 16B/lane, dest = wave-uniform base + lane*16
__device__ __forceinline__ void gl_lds16(const u16* g, u16* l) {
  __builtin_amdgcn_global_load_lds(
      (const __attribute__((address_space(1))) void*)g,
      (__attribute__((address_space(3))) void*)l,
      16, 0, 0);
}

// ---------------------------------------------------------------------------
// GEMM: C[m,n] = sum_k A[m,k] * W[n,k]  (A: 12544 x K, W: N x K, bf16)
// Tile 128x128, BK=64. 4 waves, each 64x64 (4x4 MFMA 16x16x32 frags).
// LDS: [row][chunk ^ (row&7)] (8-half chunks) -> global_load_lds compatible,
// 2-way-max bank conflicts on ds_read_b128.
// EPI: 1 = bf16 store C[m*ldc+col+coloff]
//      2 = bf16 store with h<->w involution on row (vertical scatter)
// AMAP: 0 identity A rows; 1 = h<->w involution gather on A rows.
// ---------------------------------------------------------------------------
template<int EPI, int AMAP>
__global__ __launch_bounds__(256, 2)
void gemm_bt(const u16* __restrict__ A, const u16* __restrict__ W,
             u16* __restrict__ Cb, int K, int ldc, int coloff)
{
  __shared__ u16 As[128 * 64];
  __shared__ u16 Bs[128 * 64];

  const int tid  = threadIdx.x;
  const int lane = tid & 63;
  const int wv   = tid >> 6;      // 0..3
  const int wm   = wv >> 1;       // 0..1
  const int wn   = wv & 1;        // 0..1
  const int m0   = blockIdx.y * 128;
  const int n0   = blockIdx.x * 128;

  // staging geometry: per wave-instr, 64 lanes cover 8 rows x 8 chunks
  const int lr   = lane >> 3;            // row-in-group 0..7
  const int lc   = lane & 7;             // dest chunk 0..7
  const int kcol = (lc ^ lr) << 3;       // swizzled source k-chunk * 8

  int arow[4], brow[4];
#pragma unroll
  for (int i = 0; i < 4; ++i) {
    int r = m0 + wv * 32 + i * 8 + lr;
    if (AMAP == 1) {
      int b = r / 196; int q = r - b * 196;
      int wq = q / 14; int hq = q - wq * 14;
      r = b * 196 + hq * 14 + wq;
    }
    arow[i] = r;
    brow[i] = n0 + wv * 32 + i * 8 + lr;
  }

  const ffrag fz = {0.f, 0.f, 0.f, 0.f};
  ffrag acc[4][4];
#pragma unroll
  for (int i = 0; i < 4; ++i)
#pragma unroll
    for (int j = 0; j < 4; ++j) acc[i][j] = fz;

  const int fr = lane & 15;   // frag row/col within 16
  const int fq = lane >> 4;   // quad 0..3

  for (int kb = 0; kb < K; kb += 64) {
#pragma unroll
    for (int i = 0; i < 4; ++i)
      gl_lds16(A + (size_t)arow[i] * K + kb + kcol, &As[(wv * 4 + i) * 512]);
#pragma unroll
    for (int i = 0; i < 4; ++i)
      gl_lds16(W + (size_t)brow[i] * K + kb + kcol, &Bs[(wv * 4 + i) * 512]);
    __syncthreads();

#pragma unroll
    for (int ks = 0; ks < 2; ++ks) {
      bfrag af[4], bfr[4];
#pragma unroll
      for (int t = 0; t < 4; ++t) {
        int r  = wm * 64 + t * 16 + fr;
        int ca = ((ks * 4 + fq) ^ (r & 7)) << 3;
        af[t]  = *(const bfrag*)&As[r * 64 + ca];
        int n  = wn * 64 + t * 16 + fr;
        int cb = ((ks * 4 + fq) ^ (n & 7)) << 3;
        bfr[t] = *(const bfrag*)&Bs[n * 64 + cb];
      }
#pragma unroll
      for (int i = 0; i < 4; ++i)
#pragma unroll
        for (int j = 0; j < 4; ++j)
          acc[i][j] = __builtin_amdgcn_mfma_f32_16x16x32_bf16(
              af[i], bfr[j], acc[i][j], 0, 0, 0);
    }
    __syncthreads();
  }

  // epilogue: C/D layout col=lane&15, row=quad*4+reg (m89-verified)
#pragma unroll
  for (int i = 0; i < 4; ++i) {
#pragma unroll
    for (int j = 0; j < 4; ++j) {
#pragma unroll
      for (int rg = 0; rg < 4; ++rg) {
        int row = m0 + wm * 64 + i * 16 + fq * 4 + rg;
        int col = n0 + wn * 64 + j * 16 + fr + coloff;
        int orow = row;
        if (EPI == 2) {
          int b = row / 196; int q = row - b * 196;
          int wq = q / 14; int hq = q - wq * 14;
          orow = b * 196 + hq * 14 + wq;
        }
        Cb[(size_t)orow * ldc + col] = f2b(acc[i][j][rg]);
      }
    }
  }
}

// ---------------------------------------------------------------------------
// weight conversion f32 -> bf16, 7 regions per layer (contiguous dest WB)
// ---------------------------------------------------------------------------
__global__ __launch_bounds__(256)
void k_cvt7(const float* __restrict__ s0, const float* __restrict__ s1,
            const float* __restrict__ s2, const float* __restrict__ s3,
            const float* __restrict__ s4, const float* __restrict__ s5,
            const float* __restrict__ s6, u16* __restrict__ dst)
{
  int e = (blockIdx.x * 256 + threadIdx.x) * 8;   // < 4063232
  const float* s; int off;
  if      (e <  786432) { s = s0; off = e; }
  else if (e < 1376256) { s = s1; off = e -  786432; }
  else if (e < 1769472) { s = s2; off = e - 1376256; }
  else if (e < 2555904) { s = s3; off = e - 1769472; }
  else if (e < 3145728) { s = s4; off = e - 2555904; }
  else if (e < 3538944) { s = s5; off = e - 3145728; }
  else                  { s = s6; off = e - 3538944; }
  float4 a = *(const float4*)(s + off);
  float4 b = *(const float4*)(s + off + 4);
  u16x8 o;
  o[0] = f2b(a.x); o[1] = f2b(a.y); o[2] = f2b(a.z); o[3] = f2b(a.w);
  o[4] = f2b(b.x); o[5] = f2b(b.y); o[6] = f2b(b.z); o[7] = f2b(b.w);
  *(u16x8*)(dst + e) = o;
}

// single-region f32 -> bf16 (patch_w)
__global__ __launch_bounds__(256)
void k_cvt1(const float* __restrict__ s, u16* __restrict__ dst)
{
  int e = (blockIdx.x * 256 + threadIdx.x) * 8;
  float4 a = *(const float4*)(s + e);
  float4 b = *(const float4*)(s + e + 4);
  u16x8 o;
  o[0] = f2b(a.x); o[1] = f2b(a.y); o[2] = f2b(a.z); o[3] = f2b(a.w);
  o[4] = f2b(b.x); o[5] = f2b(b.y); o[6] = f2b(b.z); o[7] = f2b(b.w);
  *(u16x8*)(dst + e) = o;
}

// ---------------------------------------------------------------------------
// im2col: im[p, k=c*256+i*16+j] = x[b, c, ph*16+i, pw*16+j], 8 elems/thread
// ---------------------------------------------------------------------------
__global__ __launch_bounds__(256) void k_im2col(const float* __restrict__ x,
                                                u16* __restrict__ im)
{
  int idx = blockIdx.x * 256 + threadIdx.x;     // 12544*96
  int r = idx % 96, p = idx / 96;
  int b = p / 196, q = p - b * 196;
  int ph = q / 14, pw = q - ph * 14;
  int k = r * 8;
  int c = k >> 8, k2 = k & 255;
  int i = k2 >> 4, j = k2 & 15;                 // j in {0,8}
  const float* src = x + (((size_t)(b * 3 + c) * 224 + ph * 16 + i) * 224
                          + pw * 16 + j);
  float4 a = *(const float4*)src;
  float4 d = *(const float4*)(src + 4);
  u16x8 o;
  o[0] = f2b(a.x); o[1] = f2b(a.y); o[2] = f2b(a.z); o[3] = f2b(a.w);
  o[4] = f2b(d.x); o[5] = f2b(d.y); o[6] = f2b(d.z); o[7] = f2b(d.w);
  *(u16x8*)(im + (size_t)p * 768 + k) = o;
}

// TOK[p,n] += patch_b[n] + pos_embed[1 + p%196, n]   (bf16 RMW, 8/thread)
__global__ __launch_bounds__(256) void k_addbias(u16* __restrict__ TOK,
                                                 const float* __restrict__ pb,
                                                 const float* __restrict__ pos)
{
  int idx = blockIdx.x * 256 + threadIdx.x;     // 12544*64
  int p = idx >> 6, n = (idx & 63) * 8;
  int tpos = 1 + (p % 196);
  u16x8 t = *(u16x8*)(TOK + (size_t)p * 512 + n);
  const float* pbv = pb + n;
  const float* pv  = pos + (size_t)tpos * 512 + n;
  u16x8 o;
#pragma unroll
  for (int i = 0; i < 8; ++i) o[i] = f2b(b2f(t[i]) + pbv[i] + pv[i]);
  *(u16x8*)(TOK + (size_t)p * 512 + n) = o;
}

// in-place LN over 512 cols, one wave per row, 8 elems/lane (bf16; f32 params)
__global__ __launch_bounds__(256) void k_ln(u16* __restrict__ T,
                                            const float* __restrict__ w,
                                            const float* __restrict__ b)
{
  int row  = blockIdx.x * 4 + (threadIdx.x >> 6);
  int lane = threadIdx.x & 63;
  int base = lane * 8;
  u16* p = T + (size_t)row * 512 + base;
  u16x8 t = *(u16x8*)p;
  float v[8]; float s = 0.f, qq = 0.f;
#pragma unroll
  for (int i = 0; i < 8; ++i) { v[i] = b2f(t[i]); s += v[i]; qq += v[i] * v[i]; }
#pragma unroll
  for (int o = 32; o; o >>= 1) { s += __shfl_xor(s, o, 64); qq += __shfl_xor(qq, o, 64); }
  float mean = s * (1.f / 512.f);
  float rstd = rsqrtf(qq * (1.f / 512.f) - mean * mean + 1e-5f);
  u16x8 ov;
#pragma unroll
  for (int i = 0; i < 8; ++i)
    ov[i] = f2b((v[i] - mean) * rstd * w[base + i] + b[base + i]);
  *(u16x8*)p = ov;
}

// TOK = LN(YF + fus_b + TOK) with ss params (in place)
__global__ __launch_bounds__(256) void k_ln_fuse(const u16* __restrict__ YF,
                                                 u16* __restrict__ TOK,
                                                 const float* __restrict__ fb,
                                                 const float* __restrict__ w,
                                                 const float* __restrict__ b)
{
  int row  = blockIdx.x * 4 + (threadIdx.x >> 6);
  int lane = threadIdx.x & 63;
  int base = lane * 8;
  const u16* yf = YF + (size_t)row * 512 + base;
  u16* tp = TOK + (size_t)row * 512 + base;
  u16x8 yv = *(const u16x8*)yf;
  u16x8 tv = *(u16x8*)tp;
  float v[8]; float s = 0.f, qq = 0.f;
#pragma unroll
  for (int i = 0; i < 8; ++i) {
    v[i] = b2f(yv[i]) + fb[base + i] + b2f(tv[i]);
    s += v[i]; qq += v[i] * v[i];
  }
#pragma unroll
  for (int o = 32; o; o >>= 1) { s += __shfl_xor(s, o, 64); qq += __shfl_xor(qq, o, 64); }
  float mean = s * (1.f / 512.f);
  float rstd = rsqrtf(qq * (1.f / 512.f) - mean * mean + 1e-5f);
  u16x8 ov;
#pragma unroll
  for (int i = 0; i < 8; ++i)
    ov[i] = f2b((v[i] - mean) * rstd * w[base + i] + b[base + i]);
  *(u16x8*)tp = ov;
}

// conv3 + silu along L=14 (bf16 act, f32 params). XZ xi-half is input.
__global__ __launch_bounds__(256) void k_conv(const u16* __restrict__ XZ,
                                              const float* __restrict__ cw,
                                              const float* __restrict__ cb,
                                              u16* __restrict__ XC)
{
  int idx = blockIdx.x * 256 + threadIdx.x;   // 896*768
  int d = idx % 768, sq = idx / 768;
  const u16* xi = XZ + (size_t)sq * 14 * 1536 + d;
  float w0 = cw[d * 3 + 0], w1 = cw[d * 3 + 1], w2 = cw[d * 3 + 2];
  float bb = cb[d];
  float prev = 0.f, cur = b2f(xi[0]), nxt;
#pragma unroll
  for (int l = 0; l < 14; ++l) {
    nxt = (l < 13) ? b2f(xi[(size_t)(l + 1) * 1536]) : 0.f;
    float u = prev * w0 + cur * w1 + nxt * w2 + bb;
    XC[((size_t)sq * 14 + l) * 768 + d] = f2b(fsilu(u));
    prev = cur; cur = nxt;
  }
}

// selective-scan: dt=softplus(dtraw+db); Ae=exp(A dt); run=cumsum(xc dt Ae);
// y = (run*Ae + xc*D) * silu(z). In-place: XC holds xc in, y out.
__global__ __launch_bounds__(256) void k_scan(const u16* __restrict__ XZ,
                                              u16* __restrict__ XC,
                                              const float* __restrict__ dtb,
                                              const float* __restrict__ Ap,
                                              const float* __restrict__ Dp)
{
  int idx = blockIdx.x * 256 + threadIdx.x;   // 896*768
  int d = idx % 768, sq = idx / 768;
  float db = dtb[d], Av = Ap[d], Dv = Dp[d];
  float run = 0.f;
#pragma unroll
  for (int l = 0; l < 14; ++l) {
    size_t m = (size_t)sq * 14 + l;
    float xc = b2f(XC[m * 768 + d]);
    float dt = fsoftplus(b2f(XZ[m * 1536 + d]) + db);
    float ae = fexp(Av * dt);
    run += xc * dt * ae;
    float z = b2f(XZ[m * 1536 + 768 + d]);
    float y = (run * ae + xc * Dv) * (z * fsigmoid(z));
    XC[m * 768 + d] = f2b(y);
  }
}

// cls token path: batch-invariant, evolve one 512-vec through 6 layers (f32).
__global__ void k_cls(const float* __restrict__ cls_tok,
                      const float* __restrict__ pos,
                      const float* __restrict__ bw, const float* __restrict__ bb,
                      float* __restrict__ CLS)
{
  __shared__ float rs[8], rq[8], stat[2];
  int n = threadIdx.x;                        // 512 threads
  float v = cls_tok[n] + pos[n];
  for (int l = 0; l < 6; ++l) {
    float s = v, q = v * v;
#pragma unroll
    for (int o = 32; o; o >>= 1) { s += __shfl_xor(s, o, 64); q += __shfl_xor(q, o, 64); }
    if ((n & 63) == 0) { rs[n >> 6] = s; rq[n >> 6] = q; }
    __syncthreads();
    if (n == 0) {
      float S = 0.f, Q = 0.f;
      for (int i = 0; i < 8; ++i) { S += rs[i]; Q += rq[i]; }
      float m = S * (1.f / 512.f);
      stat[0] = m; stat[1] = rsqrtf(Q * (1.f / 512.f) - m * m + 1e-5f);
    }
    __syncthreads();
    float u = (v - stat[0]) * stat[1] * bw[l * 512 + n] + bb[l * 512 + n];
    v = v + u;
    __syncthreads();
  }
  CLS[n] = v;
}

// final LN over 64*197 tokens -> f32 out; t==0 uses the shared CLS vec.
__global__ __launch_bounds__(256) void k_final(const u16* __restrict__ TOK,
                                               const float* __restrict__ CLS,
                                               const float* __restrict__ w,
                                               const float* __restrict__ b,
                                               float* __restrict__ out)
{
  int row  = blockIdx.x * 4 + (threadIdx.x >> 6);   // < 12608
  int lane = threadIdx.x & 63;
  int bi = row / 197;
  int t  = row - bi * 197;
  int base = lane * 8;
  float v[8]; float s = 0.f, qq = 0.f;
  if (t == 0) {
#pragma unroll
    for (int i = 0; i < 8; ++i) v[i] = CLS[base + i];
  } else {
    const u16* src = TOK + ((size_t)bi * 196 + (t - 1)) * 512 + base;
    u16x8 tv = *(const u16x8*)src;
#pragma unroll
    for (int i = 0; i < 8; ++i) v[i] = b2f(tv[i]);
  }
#pragma unroll
  for (int i = 0; i < 8; ++i) { s += v[i]; qq += v[i] * v[i]; }
#pragma unroll
  for (int o = 32; o; o >>= 1) { s += __shfl_xor(s, o, 64); qq += __shfl_xor(qq, o, 64); }
  float mean = s * (1.f / 512.f);
  float rstd = rsqrtf(qq * (1.f / 512.f) - mean * mean + 1e-5f);
  float* op = out + (size_t)row * 512 + base;
#pragma unroll
  for (int i = 0; i < 8; ++i)
    op[i] = (v[i] - mean) * rstd * w[base + i] + b[base + i];
}

// ---------------------------------------------------------------------------
extern "C" void kernel_launch(void* const* d_in, const int* in_sizes, int n_in,
                              void* d_out, int out_size, void* d_ws, size_t ws_size,
                              hipStream_t stream)
{
  const float* x        = (const float*)d_in[0];
  const float* patch_w  = (const float*)d_in[1];
  const float* patch_b  = (const float*)d_in[2];
  const float* cls_tok  = (const float*)d_in[3];
  const float* pos      = (const float*)d_in[4];
  const float* blk_w    = (const float*)d_in[5];
  const float* blk_b    = (const float*)d_in[6];
  const float* mh_in_w  = (const float*)d_in[7];
  const float* mh_out_w = (const float*)d_in[8];
  const float* mh_cw    = (const float*)d_in[9];
  const float* mh_cb    = (const float*)d_in[10];
  const float* mh_dtw   = (const float*)d_in[11];
  const float* mh_dtb   = (const float*)d_in[12];
  const float* mh_A     = (const float*)d_in[13];
  const float* mh_D     = (const float*)d_in[14];
  const float* mv_in_w  = (const float*)d_in[15];
  const float* mv_out_w = (const float*)d_in[16];
  const float* mv_cw    = (const float*)d_in[17];
  const float* mv_cb    = (const float*)d_in[18];
  const float* mv_dtw   = (const float*)d_in[19];
  const float* mv_dtb   = (const float*)d_in[20];
  const float* mv_A     = (const float*)d_in[21];
  const float* mv_D     = (const float*)d_in[22];
  const float* fus_w    = (const float*)d_in[23];
  const float* fus_b    = (const float*)d_in[24];
  const float* ss_w     = (const float*)d_in[25];
  const float* ss_b     = (const float*)d_in[26];
  const float* fn_w     = (const float*)d_in[27];
  const float* fn_b     = (const float*)d_in[28];

  // workspace layout (bytes), total ~104.5 MB, all 256-aligned:
  char* ws = (char*)d_ws;
  u16*   TOK = (u16*)  (ws);                  // 12544x512  bf16  12,845,056
  u16*   XZ  = (u16*)  (ws + 12845056);       // 12544x1536 bf16  38,535,168
  u16*   XC  = (u16*)  (ws + 51380224);       // 12544x768  bf16  19,267,584
  u16*   YC  = (u16*)  (ws + 70647808);       // 12544x1024 bf16  25,690,112
  u16*   WB  = (u16*)  (ws + 96337920);       // per-layer bf16 weights 8,126,464
  float* CLS = (float*)(ws + 104464384);      // 512 f32
  u16*   IM  = XC;                            // im2col aliases XC (pre-layer)
  u16*   YF  = XZ;                            // fusion out aliases XZ

  // per-layer WB offsets (elements)
  const size_t oMHI = 0,       oMHD = 786432,  oMHO = 1376256;
  const size_t oMVI = 1769472, oMVD = 2555904, oMVO = 3145728;
  const size_t oFUS = 3538944;

  // patch embed: convert patch_w into WB, im2col, GEMM, bias/pos
  k_cvt1<<<192, 256, 0, stream>>>(patch_w, WB);
  k_im2col<<<4704, 256, 0, stream>>>(x, IM);
  gemm_bt<1, 0><<<dim3(4, 98), 256, 0, stream>>>(IM, WB, TOK, 768, 512, 0);
  k_addbias<<<3136, 256, 0, stream>>>(TOK, patch_b, pos);
  k_cls<<<1, 512, 0, stream>>>(cls_tok, pos, blk_w, blk_b, CLS);

  for (int L = 0; L < 6; ++L) {
    k_cvt7<<<1984, 256, 0, stream>>>(
        mh_in_w + (size_t)L * 786432, mh_dtw + (size_t)L * 589824,
        mh_out_w + (size_t)L * 393216,
        mv_in_w + (size_t)L * 786432, mv_dtw + (size_t)L * 589824,
        mv_out_w + (size_t)L * 393216,
        fus_w + (size_t)L * 524288, WB);

    // TOK <- LN(TOK)  (p2 = pn is the residual, so in-place is exact)
    k_ln<<<3136, 256, 0, stream>>>(TOK, blk_w + L * 512, blk_b + L * 512);

    // horizontal mamba
    gemm_bt<1, 0><<<dim3(12, 98), 256, 0, stream>>>(TOK, WB + oMHI, XZ, 512, 1536, 0);
    k_conv<<<2688, 256, 0, stream>>>(XZ, mh_cw + L * 2304, mh_cb + L * 768, XC);
    gemm_bt<1, 0><<<dim3(6, 98), 256, 0, stream>>>(XC, WB + oMHD, XZ, 768, 1536, 0);
    k_scan<<<2688, 256, 0, stream>>>(XZ, XC, mh_dtb + L * 768, mh_A + L * 768,
                                     mh_D + L * 768);
    gemm_bt<1, 0><<<dim3(4, 98), 256, 0, stream>>>(XC, WB + oMHO, YC, 768, 1024, 0);

    // vertical mamba (gather h<->w on in-proj A rows, scatter on out-proj)
    gemm_bt<1, 1><<<dim3(12, 98), 256, 0, stream>>>(TOK, WB + oMVI, XZ, 512, 1536, 0);
    k_conv<<<2688, 256, 0, stream>>>(XZ, mv_cw + L * 2304, mv_cb + L * 768, XC);
    gemm_bt<1, 0><<<dim3(6, 98), 256, 0, stream>>>(XC, WB + oMVD, XZ, 768, 1536, 0);
    k_scan<<<2688, 256, 0, stream>>>(XZ, XC, mv_dtb + L * 768, mv_A + L * 768,
                                     mv_D + L * 768);
    gemm_bt<2, 0><<<dim3(4, 98), 256, 0, stream>>>(XC, WB + oMVO, YC, 768, 1024, 512);

    // fusion + residual LN (YF aliases XZ, dead after v-scan)
    gemm_bt<1, 0><<<dim3(4, 98), 256, 0, stream>>>(YC, WB + oFUS, YF, 1024, 512, 0);
    k_ln_fuse<<<3136, 256, 0, stream>>>(YF, TOK, fus_b + L * 512, ss_w + L * 512,
                                        ss_b + L * 512);
  }

  k_final<<<3152, 256, 0, stream>>>(TOK, CLS, fn_w, fn_b, (float*)d_out);
  (void)in_sizes; (void)n_in; (void)out_size; (void)ws_size;
}

// Round 5
// 1495.662 us; speedup vs baseline: 1.5067x; 1.1427x over previous
//
#include <hip/hip_runtime.h>
#include <cstdint>

// VisionMambaLite forward on gfx950.
// R5: h/v mamba paths merged — v stays in token order (stride-14 sequences),
// so in/dt/out projections become single dual GEMMs (blockIdx.x picks the
// weight half), conv/scan are single h+v kernels, weights convert once.
// Dispatches: ~89 -> ~54. GEMMs: bf16 MFMA 16x16x32, fp32 accum.

using u16 = unsigned short;
typedef __attribute__((ext_vector_type(8))) short   bfrag;   // 8 bf16 = 4 VGPR
typedef __attribute__((ext_vector_type(4))) float   ffrag;   // 4 f32 acc
typedef __attribute__((ext_vector_type(8))) u16     u16x8;

__device__ __forceinline__ float b2f(u16 u) {
  union { float f; uint32_t i; } c; c.i = ((uint32_t)u) << 16; return c.f;
}
__device__ __forceinline__ u16 f2b(float f) {
  union { float f; uint32_t i; } c; c.f = f;
  uint32_t r = c.i + 0x7FFFu + ((c.i >> 16) & 1u);
  return (u16)(r >> 16);
}

// fast HW transcendentals
#define LOG2E 1.44269504f
#define LN2   0.69314718f
__device__ __forceinline__ float fexp(float x) {
  return __builtin_amdgcn_exp2f(x * LOG2E);
}
__device__ __forceinline__ float fsigmoid(float x) {
  return __builtin_amdgcn_rcpf(1.f + __builtin_amdgcn_exp2f(-x * LOG2E));
}
__device__ __forceinline__ float fsilu(float x) { return x * fsigmoid(x); }
__device__ __forceinline__ float fsoftplus(float x) {
  float e = __builtin_amdgcn_exp2f(-fabsf(x) * LOG2E);
  return fmaxf(x, 0.f) + LN2 * __builtin_amdgcn_logf(1.f + e);
}

// async global->LDS, 16B/lane, dest = wave-uniform base + lane*16
__device__ __forceinline__ void gl_lds16(const u16* g, u16* l) {
  __builtin_amdgcn_global_load_lds(
      (const __attribute__((address_space(1))) void*)g,
      (__attribute__((address_space(3))) void*)l,
      16, 0, 0);
}

// ---------------------------------------------------------------------------
// Dual GEMM: C[m, col] = sum_k A[m, acol+k] * W[n, k]
//   blockIdx.x < nsplit  : W = W1, acol = 0,     col = n0
//   blockIdx.x >= nsplit : W = W2, acol = acol2, col = n0' + ccol2
// Tile 128x128, BK=64. 4 waves, 64x64 each (4x4 MFMA 16x16x32 frags).
// LDS: [row][chunk ^ (row&7)] -> global_load_lds compatible, <=2-way conflicts.
// ---------------------------------------------------------------------------
__global__ __launch_bounds__(256, 2)
void gemm_dual(const u16* __restrict__ A, const u16* __restrict__ W1,
               const u16* __restrict__ W2, u16* __restrict__ C,
               int K, int lda, int ldc, int nsplit, int acol2, int ccol2)
{
  __shared__ u16 As[128 * 64];
  __shared__ u16 Bs[128 * 64];

  const int nb     = blockIdx.x;
  const bool second = nb >= nsplit;
  const u16* W     = second ? W2 : W1;
  const int n0l    = (nb - (second ? nsplit : 0)) * 128;
  const int acol   = second ? acol2 : 0;
  const int ccol0  = n0l + (second ? ccol2 : 0);
  const int m0     = blockIdx.y * 128;

  const int tid  = threadIdx.x;
  const int lane = tid & 63;
  const int wv   = tid >> 6;      // 0..3
  const int wm   = wv >> 1;       // 0..1
  const int wn   = wv & 1;        // 0..1

  // staging geometry: per wave-instr, 64 lanes cover 8 rows x 8 chunks
  const int lr   = lane >> 3;            // row-in-group 0..7
  const int lc   = lane & 7;             // dest chunk 0..7
  const int kcol = (lc ^ lr) << 3;       // swizzled source k-chunk * 8

  const size_t abase = (size_t)(m0 + wv * 32 + lr) * lda + acol + kcol;
  const size_t wbase = (size_t)(n0l + wv * 32 + lr) * K + kcol;

  const ffrag fz = {0.f, 0.f, 0.f, 0.f};
  ffrag acc[4][4];
#pragma unroll
  for (int i = 0; i < 4; ++i)
#pragma unroll
    for (int j = 0; j < 4; ++j) acc[i][j] = fz;

  const int fr = lane & 15;   // frag row/col within 16
  const int fq = lane >> 4;   // quad 0..3

  for (int kb = 0; kb < K; kb += 64) {
#pragma unroll
    for (int i = 0; i < 4; ++i)
      gl_lds16(A + abase + (size_t)(i * 8) * lda + kb, &As[(wv * 4 + i) * 512]);
#pragma unroll
    for (int i = 0; i < 4; ++i)
      gl_lds16(W + wbase + (size_t)(i * 8) * K + kb, &Bs[(wv * 4 + i) * 512]);
    __syncthreads();

#pragma unroll
    for (int ks = 0; ks < 2; ++ks) {
      bfrag af[4], bfr[4];
#pragma unroll
      for (int t = 0; t < 4; ++t) {
        int r  = wm * 64 + t * 16 + fr;
        int ca = ((ks * 4 + fq) ^ (r & 7)) << 3;
        af[t]  = *(const bfrag*)&As[r * 64 + ca];
        int n  = wn * 64 + t * 16 + fr;
        int cb = ((ks * 4 + fq) ^ (n & 7)) << 3;
        bfr[t] = *(const bfrag*)&Bs[n * 64 + cb];
      }
#pragma unroll
      for (int i = 0; i < 4; ++i)
#pragma unroll
        for (int j = 0; j < 4; ++j)
          acc[i][j] = __builtin_amdgcn_mfma_f32_16x16x32_bf16(
              af[i], bfr[j], acc[i][j], 0, 0, 0);
    }
    __syncthreads();
  }

  // epilogue: C/D layout col=lane&15, row=quad*4+reg (m89-verified)
#pragma unroll
  for (int i = 0; i < 4; ++i) {
#pragma unroll
    for (int j = 0; j < 4; ++j) {
#pragma unroll
      for (int rg = 0; rg < 4; ++rg) {
        int row = m0 + wm * 64 + i * 16 + fq * 4 + rg;
        int col = ccol0 + wn * 64 + j * 16 + fr;
        C[(size_t)row * ldc + col] = f2b(acc[i][j][rg]);
      }
    }
  }
}

// ---------------------------------------------------------------------------
// weight conversion f32 -> bf16, all 6 layers x 7 regions in one dispatch.
// per-layer element offsets in dst (stride 4,063,232):
//   mh_in 0 | mh_dt 786432 | mh_out 1376256 | mv_in 1769472 |
//   mv_dt 2555904 | mv_out 3145728 | fus 3538944
// ---------------------------------------------------------------------------
__global__ __launch_bounds__(256)
void k_cvt_all(const float* __restrict__ mhi, const float* __restrict__ mhd,
               const float* __restrict__ mho, const float* __restrict__ mvi,
               const float* __restrict__ mvd, const float* __restrict__ mvo,
               const float* __restrict__ fus, u16* __restrict__ dst)
{
  size_t e = ((size_t)blockIdx.x * 256 + threadIdx.x) * 8;  // < 24,379,392
  int L = (int)(e / 4063232);
  int r = (int)(e - (size_t)L * 4063232);
  const float* s; int off;
  if      (r <  786432) { s = mhi + (size_t)L *  786432; off = r; }
  else if (r < 1376256) { s = mhd + (size_t)L *  589824; off = r -  786432; }
  else if (r < 1769472) { s = mho + (size_t)L *  393216; off = r - 1376256; }
  else if (r < 2555904) { s = mvi + (size_t)L *  786432; off = r - 1769472; }
  else if (r < 3145728) { s = mvd + (size_t)L *  589824; off = r - 2555904; }
  else if (r < 3538944) { s = mvo + (size_t)L *  393216; off = r - 3145728; }
  else                  { s = fus + (size_t)L *  524288; off = r - 3538944; }
  float4 a = *(const float4*)(s + off);
  float4 b = *(const float4*)(s + off + 4);
  u16x8 o;
  o[0] = f2b(a.x); o[1] = f2b(a.y); o[2] = f2b(a.z); o[3] = f2b(a.w);
  o[4] = f2b(b.x); o[5] = f2b(b.y); o[6] = f2b(b.z); o[7] = f2b(b.w);
  *(u16x8*)(dst + e) = o;
}

// single-region f32 -> bf16 (patch_w)
__global__ __launch_bounds__(256)
void k_cvt1(const float* __restrict__ s, u16* __restrict__ dst)
{
  int e = (blockIdx.x * 256 + threadIdx.x) * 8;
  float4 a = *(const float4*)(s + e);
  float4 b = *(const float4*)(s + e + 4);
  u16x8 o;
  o[0] = f2b(a.x); o[1] = f2b(a.y); o[2] = f2b(a.z); o[3] = f2b(a.w);
  o[4] = f2b(b.x); o[5] = f2b(b.y); o[6] = f2b(b.z); o[7] = f2b(b.w);
  *(u16x8*)(dst + e) = o;
}

// ---------------------------------------------------------------------------
// im2col: im[p, k=c*256+i*16+j] = x[b, c, ph*16+i, pw*16+j], 8 elems/thread
// ---------------------------------------------------------------------------
__global__ __launch_bounds__(256) void k_im2col(const float* __restrict__ x,
                                                u16* __restrict__ im)
{
  int idx = blockIdx.x * 256 + threadIdx.x;     // 12544*96
  int r = idx % 96, p = idx / 96;
  int b = p / 196, q = p - b * 196;
  int ph = q / 14, pw = q - ph * 14;
  int k = r * 8;
  int c = k >> 8, k2 = k & 255;
  int i = k2 >> 4, j = k2 & 15;                 // j in {0,8}
  const float* src = x + (((size_t)(b * 3 + c) * 224 + ph * 16 + i) * 224
                          + pw * 16 + j);
  float4 a = *(const float4*)src;
  float4 d = *(const float4*)(src + 4);
  u16x8 o;
  o[0] = f2b(a.x); o[1] = f2b(a.y); o[2] = f2b(a.z); o[3] = f2b(a.w);
  o[4] = f2b(d.x); o[5] = f2b(d.y); o[6] = f2b(d.z); o[7] = f2b(d.w);
  *(u16x8*)(im + (size_t)p * 768 + k) = o;
}

// TOK[p,n] += patch_b[n] + pos_embed[1 + p%196, n]   (bf16 RMW, 8/thread)
__global__ __launch_bounds__(256) void k_addbias(u16* __restrict__ TOK,
                                                 const float* __restrict__ pb,
                                                 const float* __restrict__ pos)
{
  int idx = blockIdx.x * 256 + threadIdx.x;     // 12544*64
  int p = idx >> 6, n = (idx & 63) * 8;
  int tpos = 1 + (p % 196);
  u16x8 t = *(u16x8*)(TOK + (size_t)p * 512 + n);
  const float* pbv = pb + n;
  const float* pv  = pos + (size_t)tpos * 512 + n;
  u16x8 o;
#pragma unroll
  for (int i = 0; i < 8; ++i) o[i] = f2b(b2f(t[i]) + pbv[i] + pv[i]);
  *(u16x8*)(TOK + (size_t)p * 512 + n) = o;
}

// in-place LN over 512 cols, one wave per row, 8 elems/lane (bf16; f32 params)
__global__ __launch_bounds__(256) void k_ln(u16* __restrict__ T,
                                            const float* __restrict__ w,
                                            const float* __restrict__ b)
{
  int row  = blockIdx.x * 4 + (threadIdx.x >> 6);
  int lane = threadIdx.x & 63;
  int base = lane * 8;
  u16* p = T + (size_t)row * 512 + base;
  u16x8 t = *(u16x8*)p;
  float v[8]; float s = 0.f, qq = 0.f;
#pragma unroll
  for (int i = 0; i < 8; ++i) { v[i] = b2f(t[i]); s += v[i]; qq += v[i] * v[i]; }
#pragma unroll
  for (int o = 32; o; o >>= 1) { s += __shfl_xor(s, o, 64); qq += __shfl_xor(qq, o, 64); }
  float mean = s * (1.f / 512.f);
  float rstd = rsqrtf(qq * (1.f / 512.f) - mean * mean + 1e-5f);
  u16x8 ov;
#pragma unroll
  for (int i = 0; i < 8; ++i)
    ov[i] = f2b((v[i] - mean) * rstd * w[base + i] + b[base + i]);
  *(u16x8*)p = ov;
}

// TOK = LN(YF + fus_b + TOK) with ss params (in place)
__global__ __launch_bounds__(256) void k_ln_fuse(const u16* __restrict__ YF,
                                                 u16* __restrict__ TOK,
                                                 const float* __restrict__ fb,
                                                 const float* __restrict__ w,
                                                 const float* __restrict__ b)
{
  int row  = blockIdx.x * 4 + (threadIdx.x >> 6);
  int lane = threadIdx.x & 63;
  int base = lane * 8;
  const u16* yf = YF + (size_t)row * 512 + base;
  u16* tp = TOK + (size_t)row * 512 + base;
  u16x8 yv = *(const u16x8*)yf;
  u16x8 tv = *(u16x8*)tp;
  float v[8]; float s = 0.f, qq = 0.f;
#pragma unroll
  for (int i = 0; i < 8; ++i) {
    v[i] = b2f(yv[i]) + fb[base + i] + b2f(tv[i]);
    s += v[i]; qq += v[i] * v[i];
  }
#pragma unroll
  for (int o = 32; o; o >>= 1) { s += __shfl_xor(s, o, 64); qq += __shfl_xor(qq, o, 64); }
  float mean = s * (1.f / 512.f);
  float rstd = rsqrtf(qq * (1.f / 512.f) - mean * mean + 1e-5f);
  u16x8 ov;
#pragma unroll
  for (int i = 0; i < 8; ++i)
    ov[i] = f2b((v[i] - mean) * rstd * w[base + i] + b[base + i]);
  *(u16x8*)tp = ov;
}

// ---------------------------------------------------------------------------
// conv3 + silu, h and v in one dispatch. XZ = XZHV (ld 3072), XC = XCHV (1536)
// h: seq rows sq*14+l, xi at col d;  v: rows b*196+l*14+wq, xi at col 1536+d.
// half is block-uniform (2688 blocks per half).
// ---------------------------------------------------------------------------
__global__ __launch_bounds__(256)
void k_conv_hv(const u16* __restrict__ XZ,
               const float* __restrict__ cwh, const float* __restrict__ cbh,
               const float* __restrict__ cwv, const float* __restrict__ cbv,
               u16* __restrict__ XC)
{
  int idx = blockIdx.x * 256 + threadIdx.x;   // 2*896*768
  int half = idx >= 688128;
  int t = idx - (half ? 688128 : 0);
  int d = t % 768, sq = t / 768;
  int rowbase, rowstride;
  if (!half) { rowbase = sq * 14; rowstride = 1; }
  else       { int b = sq / 14, wq = sq - b * 14; rowbase = b * 196 + wq; rowstride = 14; }
  const float* cw = half ? cwv : cwh;
  const float* cb = half ? cbv : cbh;
  int xio = half ? 1536 : 0, xco = half ? 768 : 0;
  float w0 = cw[d * 3 + 0], w1 = cw[d * 3 + 1], w2 = cw[d * 3 + 2];
  float bb = cb[d];
  float prev = 0.f, cur = b2f(XZ[(size_t)rowbase * 3072 + xio + d]), nxt;
#pragma unroll
  for (int l = 0; l < 14; ++l) {
    int row = rowbase + l * rowstride;
    nxt = (l < 13) ? b2f(XZ[(size_t)(row + rowstride) * 3072 + xio + d]) : 0.f;
    float u = prev * w0 + cur * w1 + nxt * w2 + bb;
    XC[(size_t)row * 1536 + xco + d] = f2b(fsilu(u));
    prev = cur; cur = nxt;
  }
}

// ---------------------------------------------------------------------------
// selective-scan, h and v in one dispatch. dtraw in XZ xi slot, z at +768.
// XC holds xc in, y out (in place).
// ---------------------------------------------------------------------------
__global__ __launch_bounds__(256)
void k_scan_hv(const u16* __restrict__ XZ, u16* __restrict__ XC,
               const float* __restrict__ dtbh, const float* __restrict__ Ah,
               const float* __restrict__ Dh,
               const float* __restrict__ dtbv, const float* __restrict__ Av,
               const float* __restrict__ Dv)
{
  int idx = blockIdx.x * 256 + threadIdx.x;   // 2*896*768
  int half = idx >= 688128;
  int t = idx - (half ? 688128 : 0);
  int d = t % 768, sq = t / 768;
  int rowbase, rowstride;
  if (!half) { rowbase = sq * 14; rowstride = 1; }
  else       { int b = sq / 14, wq = sq - b * 14; rowbase = b * 196 + wq; rowstride = 14; }
  int xio = half ? 1536 : 0, xco = half ? 768 : 0;
  float db = half ? dtbv[d] : dtbh[d];
  float Avv = half ? Av[d] : Ah[d];
  float Dvv = half ? Dv[d] : Dh[d];
  float run = 0.f;
#pragma unroll
  for (int l = 0; l < 14; ++l) {
    int row = rowbase + l * rowstride;
    size_t zb = (size_t)row * 3072 + xio;
    size_t cb = (size_t)row * 1536 + xco;
    float xc = b2f(XC[cb + d]);
    float dt = fsoftplus(b2f(XZ[zb + d]) + db);
    float ae = fexp(Avv * dt);
    run += xc * dt * ae;
    float z = b2f(XZ[zb + 768 + d]);
    float y = (run * ae + xc * Dvv) * (z * fsigmoid(z));
    XC[cb + d] = f2b(y);
  }
}

// cls token path: batch-invariant, evolve one 512-vec through 6 layers (f32).
__global__ void k_cls(const float* __restrict__ cls_tok,
                      const float* __restrict__ pos,
                      const float* __restrict__ bw, const float* __restrict__ bb,
                      float* __restrict__ CLS)
{
  __shared__ float rs[8], rq[8], stat[2];
  int n = threadIdx.x;                        // 512 threads
  float v = cls_tok[n] + pos[n];
  for (int l = 0; l < 6; ++l) {
    float s = v, q = v * v;
#pragma unroll
    for (int o = 32; o; o >>= 1) { s += __shfl_xor(s, o, 64); q += __shfl_xor(q, o, 64); }
    if ((n & 63) == 0) { rs[n >> 6] = s; rq[n >> 6] = q; }
    __syncthreads();
    if (n == 0) {
      float S = 0.f, Q = 0.f;
      for (int i = 0; i < 8; ++i) { S += rs[i]; Q += rq[i]; }
      float m = S * (1.f / 512.f);
      stat[0] = m; stat[1] = rsqrtf(Q * (1.f / 512.f) - m * m + 1e-5f);
    }
    __syncthreads();
    float u = (v - stat[0]) * stat[1] * bw[l * 512 + n] + bb[l * 512 + n];
    v = v + u;
    __syncthreads();
  }
  CLS[n] = v;
}

// final LN over 64*197 tokens -> f32 out; t==0 uses the shared CLS vec.
__global__ __launch_bounds__(256) void k_final(const u16* __restrict__ TOK,
                                               const float* __restrict__ CLS,
                                               const float* __restrict__ w,
                                               const float* __restrict__ b,
                                               float* __restrict__ out)
{
  int row  = blockIdx.x * 4 + (threadIdx.x >> 6);   // < 12608
  int lane = threadIdx.x & 63;
  int bi = row / 197;
  int t  = row - bi * 197;
  int base = lane * 8;
  float v[8]; float s = 0.f, qq = 0.f;
  if (t == 0) {
#pragma unroll
    for (int i = 0; i < 8; ++i) v[i] = CLS[base + i];
  } else {
    const u16* src = TOK + ((size_t)bi * 196 + (t - 1)) * 512 + base;
    u16x8 tv = *(const u16x8*)src;
#pragma unroll
    for (int i = 0; i < 8; ++i) v[i] = b2f(tv[i]);
  }
#pragma unroll
  for (int i = 0; i < 8; ++i) { s += v[i]; qq += v[i] * v[i]; }
#pragma unroll
  for (int o = 32; o; o >>= 1) { s += __shfl_xor(s, o, 64); qq += __shfl_xor(qq, o, 64); }
  float mean = s * (1.f / 512.f);
  float rstd = rsqrtf(qq * (1.f / 512.f) - mean * mean + 1e-5f);
  float* op = out + (size_t)row * 512 + base;
#pragma unroll
  for (int i = 0; i < 8; ++i)
    op[i] = (v[i] - mean) * rstd * w[base + i] + b[base + i];
}

// ---------------------------------------------------------------------------
extern "C" void kernel_launch(void* const* d_in, const int* in_sizes, int n_in,
                              void* d_out, int out_size, void* d_ws, size_t ws_size,
                              hipStream_t stream)
{
  const float* x        = (const float*)d_in[0];
  const float* patch_w  = (const float*)d_in[1];
  const float* patch_b  = (const float*)d_in[2];
  const float* cls_tok  = (const float*)d_in[3];
  const float* pos      = (const float*)d_in[4];
  const float* blk_w    = (const float*)d_in[5];
  const float* blk_b    = (const float*)d_in[6];
  const float* mh_in_w  = (const float*)d_in[7];
  const float* mh_out_w = (const float*)d_in[8];
  const float* mh_cw    = (const float*)d_in[9];
  const float* mh_cb    = (const float*)d_in[10];
  const float* mh_dtw   = (const float*)d_in[11];
  const float* mh_dtb   = (const float*)d_in[12];
  const float* mh_A     = (const float*)d_in[13];
  const float* mh_D     = (const float*)d_in[14];
  const float* mv_in_w  = (const float*)d_in[15];
  const float* mv_out_w = (const float*)d_in[16];
  const float* mv_cw    = (const float*)d_in[17];
  const float* mv_cb    = (const float*)d_in[18];
  const float* mv_dtw   = (const float*)d_in[19];
  const float* mv_dtb   = (const float*)d_in[20];
  const float* mv_A     = (const float*)d_in[21];
  const float* mv_D     = (const float*)d_in[22];
  const float* fus_w    = (const float*)d_in[23];
  const float* fus_b    = (const float*)d_in[24];
  const float* ss_w     = (const float*)d_in[25];
  const float* ss_b     = (const float*)d_in[26];
  const float* fn_w     = (const float*)d_in[27];
  const float* fn_b     = (const float*)d_in[28];

  // workspace layout (bytes), total ~203.7 MB (ws_size = 256 MiB):
  char* ws = (char*)d_ws;
  u16*   TOK  = (u16*)  (ws);                  // 12544x512  bf16  12,845,056
  u16*   XZHV = (u16*)  (ws +  12845056);      // 12544x3072 bf16  77,070,336
  u16*   XCHV = (u16*)  (ws +  89915392);      // 12544x1536 bf16  38,535,168
  u16*   YC   = (u16*)  (ws + 128450560);      // 12544x1024 bf16  25,690,112
  u16*   WB   = (u16*)  (ws + 154140672);      // 6-layer bf16 wts 48,758,784
  u16*   WP   = (u16*)  (ws + 202899456);      // patch_w bf16        786,432
  float* CLS  = (float*)(ws + 203685888);      // 512 f32
  u16*   IM   = XCHV;                          // im2col aliases XCHV
  u16*   YF   = XZHV;                          // fusion out aliases XZHV

  // per-layer WB offsets (elements), layer stride 4,063,232
  const size_t LS = 4063232;
  const size_t oMHI = 0,       oMHD = 786432,  oMHO = 1376256;
  const size_t oMVI = 1769472, oMVD = 2555904, oMVO = 3145728;
  const size_t oFUS = 3538944;

  // one-time: weight conversions, patch embed, cls path
  k_cvt_all<<<11904, 256, 0, stream>>>(mh_in_w, mh_dtw, mh_out_w,
                                       mv_in_w, mv_dtw, mv_out_w, fus_w, WB);
  k_cvt1<<<192, 256, 0, stream>>>(patch_w, WP);
  k_im2col<<<4704, 256, 0, stream>>>(x, IM);
  gemm_dual<<<dim3(4, 98), 256, 0, stream>>>(IM, WP, WP, TOK,
                                             768, 768, 512, 4, 0, 0);
  k_addbias<<<3136, 256, 0, stream>>>(TOK, patch_b, pos);
  k_cls<<<1, 512, 0, stream>>>(cls_tok, pos, blk_w, blk_b, CLS);

  for (int L = 0; L < 6; ++L) {
    const u16* wl = WB + (size_t)L * LS;

    // TOK <- LN(TOK)  (p2 = pn is the residual, so in-place is exact)
    k_ln<<<3136, 256, 0, stream>>>(TOK, blk_w + L * 512, blk_b + L * 512);

    // in-proj (h cols 0..1535, v cols 1536..3071)
    gemm_dual<<<dim3(24, 98), 256, 0, stream>>>(
        TOK, wl + oMHI, wl + oMVI, XZHV, 512, 512, 3072, 12, 0, 1536);
    // conv3+silu (h -> XCHV[:,0:768], v -> XCHV[:,768:1536])
    k_conv_hv<<<5376, 256, 0, stream>>>(XZHV, mh_cw + L * 2304, mh_cb + L * 768,
                                        mv_cw + L * 2304, mv_cb + L * 768, XCHV);
    // dt-proj (dtraw overwrites xi slots of XZHV)
    gemm_dual<<<dim3(12, 98), 256, 0, stream>>>(
        XCHV, wl + oMHD, wl + oMVD, XZHV, 768, 1536, 3072, 6, 768, 1536);
    // selective scan (y overwrites xc in XCHV)
    k_scan_hv<<<5376, 256, 0, stream>>>(XZHV, XCHV,
                                        mh_dtb + L * 768, mh_A + L * 768, mh_D + L * 768,
                                        mv_dtb + L * 768, mv_A + L * 768, mv_D + L * 768);
    // out-proj (h -> YC[:,0:512], v -> YC[:,512:1024])
    gemm_dual<<<dim3(8, 98), 256, 0, stream>>>(
        XCHV, wl + oMHO, wl + oMVO, YC, 768, 1536, 1024, 4, 768, 512);
    // fusion (YF aliases XZHV, dead after scan)
    gemm_dual<<<dim3(4, 98), 256, 0, stream>>>(
        YC, wl + oFUS, wl + oFUS, YF, 1024, 1024, 512, 4, 0, 0);
    // residual LN
    k_ln_fuse<<<3136, 256, 0, stream>>>(YF, TOK, fus_b + L * 512, ss_w + L * 512,
                                        ss_b + L * 512);
  }

  k_final<<<3152, 256, 0, stream>>>(TOK, CLS, fn_w, fn_b, (float*)d_out);
  (void)in_sizes; (void)n_in; (void)out_size; (void)ws_size;
}

// Round 7
// 1313.169 us; speedup vs baseline: 1.7161x; 1.1390x over previous
//
#include <hip/hip_runtime.h>
#include <cstdint>

// VisionMambaLite forward on gfx950.
// R7 = R6 with the k_cvt1 grid typo fixed (384->192 blocks; OOB read of
// patch_w caused the R6 abort).
// R6: (1) out-proj∘fusion folded into one GEMM via precomputed
// W' = [fusA@mh_out | fusB@mv_out]; (2) XCD-aware block swizzle in GEMMs;
// (3) ln_fuse+ln and addbias+ln fusions; (4) bf16x2 scan/conv.

using u16 = unsigned short;
typedef __attribute__((ext_vector_type(8))) short   bfrag;
typedef __attribute__((ext_vector_type(4))) float   ffrag;
typedef __attribute__((ext_vector_type(8))) u16     u16x8;

__device__ __forceinline__ float b2f(u16 u) {
  union { float f; uint32_t i; } c; c.i = ((uint32_t)u) << 16; return c.f;
}
__device__ __forceinline__ u16 f2b(float f) {
  union { float f; uint32_t i; } c; c.f = f;
  uint32_t r = c.i + 0x7FFFu + ((c.i >> 16) & 1u);
  return (u16)(r >> 16);
}

#define LOG2E 1.44269504f
#define LN2   0.69314718f
__device__ __forceinline__ float fexp(float x) {
  return __builtin_amdgcn_exp2f(x * LOG2E);
}
__device__ __forceinline__ float fsigmoid(float x) {
  return __builtin_amdgcn_rcpf(1.f + __builtin_amdgcn_exp2f(-x * LOG2E));
}
__device__ __forceinline__ float fsilu(float x) { return x * fsigmoid(x); }
__device__ __forceinline__ float fsoftplus(float x) {
  float e = __builtin_amdgcn_exp2f(-fabsf(x) * LOG2E);
  return fmaxf(x, 0.f) + LN2 * __builtin_amdgcn_logf(1.f + e);
}

__device__ __forceinline__ void gl_lds16(const u16* g, u16* l) {
  __builtin_amdgcn_global_load_lds(
      (const __attribute__((address_space(1))) void*)g,
      (__attribute__((address_space(3))) void*)l,
      16, 0, 0);
}

// ---------------------------------------------------------------------------
// Dual GEMM with XCD swizzle: C[m,col] = sum_k A[m,acol+k]*W[n,k]
// grid total must be divisible by 8. Consecutive blockIdx are assumed
// round-robin across 8 XCDs -> remap so each XCD owns contiguous m-tiles.
// ---------------------------------------------------------------------------
__global__ __launch_bounds__(256, 2)
void gemm_dual(const u16* __restrict__ A, const u16* __restrict__ W1,
               const u16* __restrict__ W2, u16* __restrict__ C,
               int K, int lda, int ldc, int nsplit, int acol2, int ccol2)
{
  __shared__ u16 As[128 * 64];
  __shared__ u16 Bs[128 * 64];

  // XCD swizzle
  const int total = gridDim.x * gridDim.y;
  const int flat  = blockIdx.y * gridDim.x + blockIdx.x;
  const int chunk = total >> 3;
  const int f2    = (flat & 7) * chunk + (flat >> 3);
  const int bx    = f2 % gridDim.x;
  const int by    = f2 / gridDim.x;

  const bool second = bx >= nsplit;
  const u16* W     = second ? W2 : W1;
  const int n0l    = (bx - (second ? nsplit : 0)) * 128;
  const int acol   = second ? acol2 : 0;
  const int ccol0  = n0l + (second ? ccol2 : 0);
  const int m0     = by * 128;

  const int tid  = threadIdx.x;
  const int lane = tid & 63;
  const int wv   = tid >> 6;
  const int wm   = wv >> 1;
  const int wn   = wv & 1;

  const int lr   = lane >> 3;
  const int lc   = lane & 7;
  const int kcol = (lc ^ lr) << 3;

  const size_t abase = (size_t)(m0 + wv * 32 + lr) * lda + acol + kcol;
  const size_t wbase = (size_t)(n0l + wv * 32 + lr) * K + kcol;

  const ffrag fz = {0.f, 0.f, 0.f, 0.f};
  ffrag acc[4][4];
#pragma unroll
  for (int i = 0; i < 4; ++i)
#pragma unroll
    for (int j = 0; j < 4; ++j) acc[i][j] = fz;

  const int fr = lane & 15;
  const int fq = lane >> 4;

  for (int kb = 0; kb < K; kb += 64) {
#pragma unroll
    for (int i = 0; i < 4; ++i)
      gl_lds16(A + abase + (size_t)(i * 8) * lda + kb, &As[(wv * 4 + i) * 512]);
#pragma unroll
    for (int i = 0; i < 4; ++i)
      gl_lds16(W + wbase + (size_t)(i * 8) * K + kb, &Bs[(wv * 4 + i) * 512]);
    __syncthreads();

#pragma unroll
    for (int ks = 0; ks < 2; ++ks) {
      bfrag af[4], bfr[4];
#pragma unroll
      for (int t = 0; t < 4; ++t) {
        int r  = wm * 64 + t * 16 + fr;
        int ca = ((ks * 4 + fq) ^ (r & 7)) << 3;
        af[t]  = *(const bfrag*)&As[r * 64 + ca];
        int n  = wn * 64 + t * 16 + fr;
        int cb = ((ks * 4 + fq) ^ (n & 7)) << 3;
        bfr[t] = *(const bfrag*)&Bs[n * 64 + cb];
      }
#pragma unroll
      for (int i = 0; i < 4; ++i)
#pragma unroll
        for (int j = 0; j < 4; ++j)
          acc[i][j] = __builtin_amdgcn_mfma_f32_16x16x32_bf16(
              af[i], bfr[j], acc[i][j], 0, 0, 0);
    }
    __syncthreads();
  }

#pragma unroll
  for (int i = 0; i < 4; ++i)
#pragma unroll
    for (int j = 0; j < 4; ++j)
#pragma unroll
      for (int rg = 0; rg < 4; ++rg) {
        int row = m0 + wm * 64 + i * 16 + fq * 4 + rg;
        int col = ccol0 + wn * 64 + j * 16 + fr;
        C[(size_t)row * ldc + col] = f2b(acc[i][j][rg]);
      }
}

// ---------------------------------------------------------------------------
// W' precompute GEMM: z = L*2+path. C[c,d] = sum_{c'} fus[c, path*512+c'] *
// OT[z][d, c']  ->  WF[L][c*1536 + path*768 + d].  M=512, N=768, K=512.
// ---------------------------------------------------------------------------
__global__ __launch_bounds__(256, 2)
void gemm_wprep(const u16* __restrict__ WB, const u16* __restrict__ OT,
                u16* __restrict__ WF)
{
  __shared__ u16 As[128 * 64];
  __shared__ u16 Bs[128 * 64];

  const int z = blockIdx.z, L = z >> 1, path = z & 1;
  const u16* A = WB + (size_t)L * 4063232 + 3538944;   // fus bf16, lda 1024
  const u16* W = OT + (size_t)z * 393216;              // 768 x 512
  u16* C = WF + (size_t)L * 786432;

  const int m0 = blockIdx.y * 128, n0l = blockIdx.x * 128;
  const int acol = path * 512, ccol = path * 768;

  const int tid  = threadIdx.x;
  const int lane = tid & 63;
  const int wv   = tid >> 6;
  const int wm   = wv >> 1;
  const int wn   = wv & 1;
  const int lr   = lane >> 3;
  const int lc   = lane & 7;
  const int kcol = (lc ^ lr) << 3;

  const size_t abase = (size_t)(m0 + wv * 32 + lr) * 1024 + acol + kcol;
  const size_t wbase = (size_t)(n0l + wv * 32 + lr) * 512 + kcol;

  const ffrag fz = {0.f, 0.f, 0.f, 0.f};
  ffrag acc[4][4];
#pragma unroll
  for (int i = 0; i < 4; ++i)
#pragma unroll
    for (int j = 0; j < 4; ++j) acc[i][j] = fz;

  const int fr = lane & 15;
  const int fq = lane >> 4;

  for (int kb = 0; kb < 512; kb += 64) {
#pragma unroll
    for (int i = 0; i < 4; ++i)
      gl_lds16(A + abase + (size_t)(i * 8) * 1024 + kb, &As[(wv * 4 + i) * 512]);
#pragma unroll
    for (int i = 0; i < 4; ++i)
      gl_lds16(W + wbase + (size_t)(i * 8) * 512 + kb, &Bs[(wv * 4 + i) * 512]);
    __syncthreads();

#pragma unroll
    for (int ks = 0; ks < 2; ++ks) {
      bfrag af[4], bfr[4];
#pragma unroll
      for (int t = 0; t < 4; ++t) {
        int r  = wm * 64 + t * 16 + fr;
        int ca = ((ks * 4 + fq) ^ (r & 7)) << 3;
        af[t]  = *(const bfrag*)&As[r * 64 + ca];
        int n  = wn * 64 + t * 16 + fr;
        int cb = ((ks * 4 + fq) ^ (n & 7)) << 3;
        bfr[t] = *(const bfrag*)&Bs[n * 64 + cb];
      }
#pragma unroll
      for (int i = 0; i < 4; ++i)
#pragma unroll
        for (int j = 0; j < 4; ++j)
          acc[i][j] = __builtin_amdgcn_mfma_f32_16x16x32_bf16(
              af[i], bfr[j], acc[i][j], 0, 0, 0);
    }
    __syncthreads();
  }

#pragma unroll
  for (int i = 0; i < 4; ++i)
#pragma unroll
    for (int j = 0; j < 4; ++j)
#pragma unroll
      for (int rg = 0; rg < 4; ++rg) {
        int row = m0 + wm * 64 + i * 16 + fq * 4 + rg;
        int col = ccol + n0l + wn * 64 + j * 16 + fr;
        C[(size_t)row * 1536 + col] = f2b(acc[i][j][rg]);
      }
}

// transpose out_w: OT[z][d][c'] = out_path[L][c'][d], f32 -> bf16.
__global__ __launch_bounds__(256)
void k_transp(const float* __restrict__ mho, const float* __restrict__ mvo,
              u16* __restrict__ OT)
{
  __shared__ float ld[32][33];
  const int z = blockIdx.z, L = z >> 1, path = z & 1;
  const float* src = (path ? mvo : mho) + (size_t)L * 393216;
  u16* dst = OT + (size_t)z * 393216;
  const int tx = threadIdx.x & 31, ty = threadIdx.x >> 5;
  const int dx = blockIdx.x * 32, cy = blockIdx.y * 32;
#pragma unroll
  for (int i = 0; i < 4; ++i)
    ld[ty + 8 * i][tx] = src[(size_t)(cy + ty + 8 * i) * 768 + dx + tx];
  __syncthreads();
#pragma unroll
  for (int i = 0; i < 4; ++i)
    dst[(size_t)(dx + ty + 8 * i) * 512 + cy + tx] = f2b(ld[tx][ty + 8 * i]);
}

// ---------------------------------------------------------------------------
// weight conversion f32 -> bf16, all 6 layers x 7 regions in one dispatch.
// ---------------------------------------------------------------------------
__global__ __launch_bounds__(256)
void k_cvt_all(const float* __restrict__ mhi, const float* __restrict__ mhd,
               const float* __restrict__ mho, const float* __restrict__ mvi,
               const float* __restrict__ mvd, const float* __restrict__ mvo,
               const float* __restrict__ fus, u16* __restrict__ dst)
{
  size_t e = ((size_t)blockIdx.x * 256 + threadIdx.x) * 8;  // < 24,379,392
  int L = (int)(e / 4063232);
  int r = (int)(e - (size_t)L * 4063232);
  const float* s; int off;
  if      (r <  786432) { s = mhi + (size_t)L *  786432; off = r; }
  else if (r < 1376256) { s = mhd + (size_t)L *  589824; off = r -  786432; }
  else if (r < 1769472) { s = mho + (size_t)L *  393216; off = r - 1376256; }
  else if (r < 2555904) { s = mvi + (size_t)L *  786432; off = r - 1769472; }
  else if (r < 3145728) { s = mvd + (size_t)L *  589824; off = r - 2555904; }
  else if (r < 3538944) { s = mvo + (size_t)L *  393216; off = r - 3145728; }
  else                  { s = fus + (size_t)L *  524288; off = r - 3538944; }
  float4 a = *(const float4*)(s + off);
  float4 b = *(const float4*)(s + off + 4);
  u16x8 o;
  o[0] = f2b(a.x); o[1] = f2b(a.y); o[2] = f2b(a.z); o[3] = f2b(a.w);
  o[4] = f2b(b.x); o[5] = f2b(b.y); o[6] = f2b(b.z); o[7] = f2b(b.w);
  *(u16x8*)(dst + e) = o;
}

__global__ __launch_bounds__(256)
void k_cvt1(const float* __restrict__ s, u16* __restrict__ dst)
{
  int e = (blockIdx.x * 256 + threadIdx.x) * 8;
  float4 a = *(const float4*)(s + e);
  float4 b = *(const float4*)(s + e + 4);
  u16x8 o;
  o[0] = f2b(a.x); o[1] = f2b(a.y); o[2] = f2b(a.z); o[3] = f2b(a.w);
  o[4] = f2b(b.x); o[5] = f2b(b.y); o[6] = f2b(b.z); o[7] = f2b(b.w);
  *(u16x8*)(dst + e) = o;
}

__global__ __launch_bounds__(256) void k_im2col(const float* __restrict__ x,
                                                u16* __restrict__ im)
{
  int idx = blockIdx.x * 256 + threadIdx.x;     // 12544*96
  int r = idx % 96, p = idx / 96;
  int b = p / 196, q = p - b * 196;
  int ph = q / 14, pw = q - ph * 14;
  int k = r * 8;
  int c = k >> 8, k2 = k & 255;
  int i = k2 >> 4, j = k2 & 15;
  const float* src = x + (((size_t)(b * 3 + c) * 224 + ph * 16 + i) * 224
                          + pw * 16 + j);
  float4 a = *(const float4*)src;
  float4 d = *(const float4*)(src + 4);
  u16x8 o;
  o[0] = f2b(a.x); o[1] = f2b(a.y); o[2] = f2b(a.z); o[3] = f2b(a.w);
  o[4] = f2b(d.x); o[5] = f2b(d.y); o[6] = f2b(d.z); o[7] = f2b(d.w);
  *(u16x8*)(im + (size_t)p * 768 + k) = o;
}

// TOK = LN_blk0(TOK + patch_b + pos), in place (fused addbias + first LN)
__global__ __launch_bounds__(256)
void k_addbias_ln(u16* __restrict__ TOK, const float* __restrict__ pb,
                  const float* __restrict__ pos, const float* __restrict__ w,
                  const float* __restrict__ b)
{
  int row  = blockIdx.x * 4 + (threadIdx.x >> 6);
  int lane = threadIdx.x & 63;
  int base = lane * 8;
  int tpos = 1 + (row % 196);
  u16* p = TOK + (size_t)row * 512 + base;
  u16x8 t = *(u16x8*)p;
  const float* pv = pos + (size_t)tpos * 512 + base;
  float v[8]; float s = 0.f, qq = 0.f;
#pragma unroll
  for (int i = 0; i < 8; ++i) {
    v[i] = b2f(t[i]) + pb[base + i] + pv[i];
    s += v[i]; qq += v[i] * v[i];
  }
#pragma unroll
  for (int o = 32; o; o >>= 1) { s += __shfl_xor(s, o, 64); qq += __shfl_xor(qq, o, 64); }
  float mean = s * (1.f / 512.f);
  float rstd = rsqrtf(qq * (1.f / 512.f) - mean * mean + 1e-5f);
  u16x8 ov;
#pragma unroll
  for (int i = 0; i < 8; ++i)
    ov[i] = f2b((v[i] - mean) * rstd * w[base + i] + b[base + i]);
  *(u16x8*)p = ov;
}

// TOK = LN_ss(YF + fus_b + TOK)  [plain, used for last layer]
__global__ __launch_bounds__(256) void k_ln_fuse(const u16* __restrict__ YF,
                                                 u16* __restrict__ TOK,
                                                 const float* __restrict__ fb,
                                                 const float* __restrict__ w,
                                                 const float* __restrict__ b)
{
  int row  = blockIdx.x * 4 + (threadIdx.x >> 6);
  int lane = threadIdx.x & 63;
  int base = lane * 8;
  const u16* yf = YF + (size_t)row * 512 + base;
  u16* tp = TOK + (size_t)row * 512 + base;
  u16x8 yv = *(const u16x8*)yf;
  u16x8 tv = *(u16x8*)tp;
  float v[8]; float s = 0.f, qq = 0.f;
#pragma unroll
  for (int i = 0; i < 8; ++i) {
    v[i] = b2f(yv[i]) + fb[base + i] + b2f(tv[i]);
    s += v[i]; qq += v[i] * v[i];
  }
#pragma unroll
  for (int o = 32; o; o >>= 1) { s += __shfl_xor(s, o, 64); qq += __shfl_xor(qq, o, 64); }
  float mean = s * (1.f / 512.f);
  float rstd = rsqrtf(qq * (1.f / 512.f) - mean * mean + 1e-5f);
  u16x8 ov;
#pragma unroll
  for (int i = 0; i < 8; ++i)
    ov[i] = f2b((v[i] - mean) * rstd * w[base + i] + b[base + i]);
  *(u16x8*)tp = ov;
}

// TOK = LN_blk(LN_ss(YF + fus_b + TOK))  (fused; t stays in f32 regs)
__global__ __launch_bounds__(256)
void k_ln_fuse2(const u16* __restrict__ YF, u16* __restrict__ TOK,
                const float* __restrict__ fb, const float* __restrict__ w1,
                const float* __restrict__ b1, const float* __restrict__ w2,
                const float* __restrict__ b2)
{
  int row  = blockIdx.x * 4 + (threadIdx.x >> 6);
  int lane = threadIdx.x & 63;
  int base = lane * 8;
  const u16* yf = YF + (size_t)row * 512 + base;
  u16* tp = TOK + (size_t)row * 512 + base;
  u16x8 yv = *(const u16x8*)yf;
  u16x8 tv = *(u16x8*)tp;
  float v[8]; float s = 0.f, qq = 0.f;
#pragma unroll
  for (int i = 0; i < 8; ++i) {
    v[i] = b2f(yv[i]) + fb[base + i] + b2f(tv[i]);
    s += v[i]; qq += v[i] * v[i];
  }
#pragma unroll
  for (int o = 32; o; o >>= 1) { s += __shfl_xor(s, o, 64); qq += __shfl_xor(qq, o, 64); }
  float mean = s * (1.f / 512.f);
  float rstd = rsqrtf(qq * (1.f / 512.f) - mean * mean + 1e-5f);
  float s2 = 0.f, q2 = 0.f;
#pragma unroll
  for (int i = 0; i < 8; ++i) {
    v[i] = (v[i] - mean) * rstd * w1[base + i] + b1[base + i];
    s2 += v[i]; q2 += v[i] * v[i];
  }
#pragma unroll
  for (int o = 32; o; o >>= 1) { s2 += __shfl_xor(s2, o, 64); q2 += __shfl_xor(q2, o, 64); }
  float m2 = s2 * (1.f / 512.f);
  float r2 = rsqrtf(q2 * (1.f / 512.f) - m2 * m2 + 1e-5f);
  u16x8 ov;
#pragma unroll
  for (int i = 0; i < 8; ++i)
    ov[i] = f2b((v[i] - m2) * r2 * w2[base + i] + b2[base + i]);
  *(u16x8*)tp = ov;
}

// conv3+silu, h+v, 2 d's per thread (u32 bf16x2)
__global__ __launch_bounds__(256)
void k_conv_hv(const u16* __restrict__ XZ,
               const float* __restrict__ cwh, const float* __restrict__ cbh,
               const float* __restrict__ cwv, const float* __restrict__ cbv,
               u16* __restrict__ XC)
{
  int idx = blockIdx.x * 256 + threadIdx.x;   // 2*896*384
  int half = idx >= 344064;
  int t = idx - (half ? 344064 : 0);
  int dp = t % 384, sq = t / 384;
  int d0 = dp * 2;
  int rowbase, rowstride;
  if (!half) { rowbase = sq * 14; rowstride = 1; }
  else       { int b = sq / 14, wq = sq - b * 14; rowbase = b * 196 + wq; rowstride = 14; }
  const float* cw = half ? cwv : cwh;
  const float* cb = half ? cbv : cbh;
  int xio = half ? 1536 : 0, xco = half ? 768 : 0;
  float w0a = cw[d0 * 3 + 0], w1a = cw[d0 * 3 + 1], w2a = cw[d0 * 3 + 2];
  float w0b = cw[d0 * 3 + 3], w1b = cw[d0 * 3 + 4], w2b = cw[d0 * 3 + 5];
  float ba = cb[d0], bb = cb[d0 + 1];
  uint32_t cu = *(const uint32_t*)&XZ[(size_t)rowbase * 3072 + xio + d0];
  float pa = 0.f, pb = 0.f;
  float ca = b2f((u16)cu), cbv2 = b2f((u16)(cu >> 16));
#pragma unroll
  for (int l = 0; l < 14; ++l) {
    int row = rowbase + l * rowstride;
    float na = 0.f, nb = 0.f;
    if (l < 13) {
      uint32_t nu = *(const uint32_t*)&XZ[(size_t)(row + rowstride) * 3072 + xio + d0];
      na = b2f((u16)nu); nb = b2f((u16)(nu >> 16));
    }
    float ua = pa * w0a + ca * w1a + na * w2a + ba;
    float ub = pb * w0b + cbv2 * w1b + nb * w2b + bb;
    uint32_t ov = (uint32_t)f2b(fsilu(ua)) | ((uint32_t)f2b(fsilu(ub)) << 16);
    *(uint32_t*)&XC[(size_t)row * 1536 + xco + d0] = ov;
    pa = ca; pb = cbv2; ca = na; cbv2 = nb;
  }
}

// selective scan, h+v, 2 d's per thread
__global__ __launch_bounds__(256)
void k_scan_hv(const u16* __restrict__ XZ, u16* __restrict__ XC,
               const float* __restrict__ dtbh, const float* __restrict__ Ah,
               const float* __restrict__ Dh,
               const float* __restrict__ dtbv, const float* __restrict__ Av,
               const float* __restrict__ Dv)
{
  int idx = blockIdx.x * 256 + threadIdx.x;   // 2*896*384
  int half = idx >= 344064;
  int t = idx - (half ? 344064 : 0);
  int dp = t % 384, sq = t / 384;
  int d0 = dp * 2;
  int rowbase, rowstride;
  if (!half) { rowbase = sq * 14; rowstride = 1; }
  else       { int b = sq / 14, wq = sq - b * 14; rowbase = b * 196 + wq; rowstride = 14; }
  int xio = half ? 1536 : 0, xco = half ? 768 : 0;
  const float* dtb = half ? dtbv : dtbh;
  const float* Ap  = half ? Av : Ah;
  const float* Dp  = half ? Dv : Dh;
  float dba = dtb[d0], dbb = dtb[d0 + 1];
  float Aa = Ap[d0], Ab = Ap[d0 + 1];
  float Da = Dp[d0], Db = Dp[d0 + 1];
  float ra = 0.f, rb = 0.f;
#pragma unroll
  for (int l = 0; l < 14; ++l) {
    int row = rowbase + l * rowstride;
    size_t zb = (size_t)row * 3072 + xio;
    size_t cbo = (size_t)row * 1536 + xco;
    uint32_t xcu = *(const uint32_t*)&XC[cbo + d0];
    uint32_t dtu = *(const uint32_t*)&XZ[zb + d0];
    uint32_t zu  = *(const uint32_t*)&XZ[zb + 768 + d0];
    float xca = b2f((u16)xcu), xcb = b2f((u16)(xcu >> 16));
    float dta = fsoftplus(b2f((u16)dtu) + dba);
    float dtbv2 = fsoftplus(b2f((u16)(dtu >> 16)) + dbb);
    float aea = fexp(Aa * dta), aeb = fexp(Ab * dtbv2);
    ra += xca * dta * aea;
    rb += xcb * dtbv2 * aeb;
    float za = b2f((u16)zu), zbv = b2f((u16)(zu >> 16));
    float ya = (ra * aea + xca * Da) * (za * fsigmoid(za));
    float yb = (rb * aeb + xcb * Db) * (zbv * fsigmoid(zbv));
    *(uint32_t*)&XC[cbo + d0] = (uint32_t)f2b(ya) | ((uint32_t)f2b(yb) << 16);
  }
}

// cls token path (batch-invariant, f32)
__global__ void k_cls(const float* __restrict__ cls_tok,
                      const float* __restrict__ pos,
                      const float* __restrict__ bw, const float* __restrict__ bb,
                      float* __restrict__ CLS)
{
  __shared__ float rs[8], rq[8], stat[2];
  int n = threadIdx.x;
  float v = cls_tok[n] + pos[n];
  for (int l = 0; l < 6; ++l) {
    float s = v, q = v * v;
#pragma unroll
    for (int o = 32; o; o >>= 1) { s += __shfl_xor(s, o, 64); q += __shfl_xor(q, o, 64); }
    if ((n & 63) == 0) { rs[n >> 6] = s; rq[n >> 6] = q; }
    __syncthreads();
    if (n == 0) {
      float S = 0.f, Q = 0.f;
      for (int i = 0; i < 8; ++i) { S += rs[i]; Q += rq[i]; }
      float m = S * (1.f / 512.f);
      stat[0] = m; stat[1] = rsqrtf(Q * (1.f / 512.f) - m * m + 1e-5f);
    }
    __syncthreads();
    float u = (v - stat[0]) * stat[1] * bw[l * 512 + n] + bb[l * 512 + n];
    v = v + u;
    __syncthreads();
  }
  CLS[n] = v;
}

// final LN -> f32 out
__global__ __launch_bounds__(256) void k_final(const u16* __restrict__ TOK,
                                               const float* __restrict__ CLS,
                                               const float* __restrict__ w,
                                               const float* __restrict__ b,
                                               float* __restrict__ out)
{
  int row  = blockIdx.x * 4 + (threadIdx.x >> 6);   // < 12608
  int lane = threadIdx.x & 63;
  int bi = row / 197;
  int t  = row - bi * 197;
  int base = lane * 8;
  float v[8]; float s = 0.f, qq = 0.f;
  if (t == 0) {
#pragma unroll
    for (int i = 0; i < 8; ++i) v[i] = CLS[base + i];
  } else {
    const u16* src = TOK + ((size_t)bi * 196 + (t - 1)) * 512 + base;
    u16x8 tv = *(const u16x8*)src;
#pragma unroll
    for (int i = 0; i < 8; ++i) v[i] = b2f(tv[i]);
  }
#pragma unroll
  for (int i = 0; i < 8; ++i) { s += v[i]; qq += v[i] * v[i]; }
#pragma unroll
  for (int o = 32; o; o >>= 1) { s += __shfl_xor(s, o, 64); qq += __shfl_xor(qq, o, 64); }
  float mean = s * (1.f / 512.f);
  float rstd = rsqrtf(qq * (1.f / 512.f) - mean * mean + 1e-5f);
  float* op = out + (size_t)row * 512 + base;
#pragma unroll
  for (int i = 0; i < 8; ++i)
    op[i] = (v[i] - mean) * rstd * w[base + i] + b[base + i];
}

// ---------------------------------------------------------------------------
extern "C" void kernel_launch(void* const* d_in, const int* in_sizes, int n_in,
                              void* d_out, int out_size, void* d_ws, size_t ws_size,
                              hipStream_t stream)
{
  const float* x        = (const float*)d_in[0];
  const float* patch_w  = (const float*)d_in[1];
  const float* patch_b  = (const float*)d_in[2];
  const float* cls_tok  = (const float*)d_in[3];
  const float* pos      = (const float*)d_in[4];
  const float* blk_w    = (const float*)d_in[5];
  const float* blk_b    = (const float*)d_in[6];
  const float* mh_in_w  = (const float*)d_in[7];
  const float* mh_out_w = (const float*)d_in[8];
  const float* mh_cw    = (const float*)d_in[9];
  const float* mh_cb    = (const float*)d_in[10];
  const float* mh_dtw   = (const float*)d_in[11];
  const float* mh_dtb   = (const float*)d_in[12];
  const float* mh_A     = (const float*)d_in[13];
  const float* mh_D     = (const float*)d_in[14];
  const float* mv_in_w  = (const float*)d_in[15];
  const float* mv_out_w = (const float*)d_in[16];
  const float* mv_cw    = (const float*)d_in[17];
  const float* mv_cb    = (const float*)d_in[18];
  const float* mv_dtw   = (const float*)d_in[19];
  const float* mv_dtb   = (const float*)d_in[20];
  const float* mv_A     = (const float*)d_in[21];
  const float* mv_D     = (const float*)d_in[22];
  const float* fus_w    = (const float*)d_in[23];
  const float* fus_b    = (const float*)d_in[24];
  const float* ss_w     = (const float*)d_in[25];
  const float* ss_b     = (const float*)d_in[26];
  const float* fn_w     = (const float*)d_in[27];
  const float* fn_b     = (const float*)d_in[28];

  // workspace layout (bytes), total ~198 MB (ws_size = 256 MiB):
  char* ws = (char*)d_ws;
  u16*   TOK  = (u16*)  (ws);                  // 12544x512  bf16  12,845,056
  u16*   XZHV = (u16*)  (ws +  12845056);      // 12544x3072 bf16  77,070,336
  u16*   XCHV = (u16*)  (ws +  89915392);      // 12544x1536 bf16  38,535,168
  u16*   WB   = (u16*)  (ws + 128450560);      // 6-layer bf16 wts 48,758,784
  u16*   WP   = (u16*)  (ws + 177209344);      // patch_w bf16        786,432
  u16*   OT   = (u16*)  (ws + 178782208);      // out^T bf16        9,437,184
  u16*   WF   = (u16*)  (ws + 188219392);      // W' fused          9,437,184
  float* CLS  = (float*)(ws + 197656576);      // 512 f32
  u16*   IM   = XCHV;                          // im2col aliases XCHV
  u16*   YF   = XZHV;                          // yf GEMM out aliases XZHV

  const size_t LS = 4063232;
  const size_t oMHI = 0, oMHD = 786432, oMVI = 1769472, oMVD = 2555904;

  // one-time: conversions, W' precompute, patch embed, cls
  k_cvt_all<<<11904, 256, 0, stream>>>(mh_in_w, mh_dtw, mh_out_w,
                                       mv_in_w, mv_dtw, mv_out_w, fus_w, WB);
  k_transp<<<dim3(24, 16, 12), 256, 0, stream>>>(mh_out_w, mv_out_w, OT);
  gemm_wprep<<<dim3(6, 4, 12), 256, 0, stream>>>(WB, OT, WF);
  k_cvt1<<<192, 256, 0, stream>>>(patch_w, WP);   // 393,216 elems exactly
  k_im2col<<<4704, 256, 0, stream>>>(x, IM);
  gemm_dual<<<dim3(4, 98), 256, 0, stream>>>(IM, WP, WP, TOK,
                                             768, 768, 512, 4, 0, 0);
  k_addbias_ln<<<3136, 256, 0, stream>>>(TOK, patch_b, pos, blk_w, blk_b);
  k_cls<<<1, 512, 0, stream>>>(cls_tok, pos, blk_w, blk_b, CLS);

  for (int L = 0; L < 6; ++L) {
    const u16* wl = WB + (size_t)L * LS;

    // in-proj (h cols 0..1535, v cols 1536..3071)
    gemm_dual<<<dim3(24, 98), 256, 0, stream>>>(
        TOK, wl + oMHI, wl + oMVI, XZHV, 512, 512, 3072, 12, 0, 1536);
    // conv3+silu
    k_conv_hv<<<2688, 256, 0, stream>>>(XZHV, mh_cw + L * 2304, mh_cb + L * 768,
                                        mv_cw + L * 2304, mv_cb + L * 768, XCHV);
    // dt-proj (dtraw overwrites xi slots of XZHV)
    gemm_dual<<<dim3(12, 98), 256, 0, stream>>>(
        XCHV, wl + oMHD, wl + oMVD, XZHV, 768, 1536, 3072, 6, 768, 1536);
    // selective scan (y overwrites xc in XCHV)
    k_scan_hv<<<2688, 256, 0, stream>>>(XZHV, XCHV,
                                        mh_dtb + L * 768, mh_A + L * 768, mh_D + L * 768,
                                        mv_dtb + L * 768, mv_A + L * 768, mv_D + L * 768);
    // fused out-proj + fusion: yf = XCHV @ W'^T  (K=1536, N=512)
    gemm_dual<<<dim3(4, 98), 256, 0, stream>>>(
        XCHV, WF + (size_t)L * 786432, WF + (size_t)L * 786432, YF,
        1536, 1536, 512, 4, 0, 0);
    // residual LN (+ next layer's LN fused, except last layer)
    if (L < 5) {
      k_ln_fuse2<<<3136, 256, 0, stream>>>(YF, TOK, fus_b + L * 512,
                                           ss_w + L * 512, ss_b + L * 512,
                                           blk_w + (L + 1) * 512, blk_b + (L + 1) * 512);
    } else {
      k_ln_fuse<<<3136, 256, 0, stream>>>(YF, TOK, fus_b + L * 512,
                                          ss_w + L * 512, ss_b + L * 512);
    }
  }

  k_final<<<3152, 256, 0, stream>>>(TOK, CLS, fn_w, fn_b, (float*)d_out);
  (void)in_sizes; (void)n_in; (void)out_size; (void)ws_size;
}